// Round 1
// baseline (1590.544 us; speedup 1.0000x reference)
//
#include <hip/hip_runtime.h>
#include <hip/hip_bf16.h>

// ---------------- constants ----------------
#define TT 128
#define BB 64
#define DD 64
#define RR 20
#define SEE 10
#define HH 4
#define CC 4
#define NITEM (TT*BB*SEE)     // 81920
static __device__ __forceinline__ float wave_sum(float v) {
  v += __shfl_xor(v, 32); v += __shfl_xor(v, 16); v += __shfl_xor(v, 8);
  v += __shfl_xor(v, 4);  v += __shfl_xor(v, 2);  v += __shfl_xor(v, 1);
  return v;
}
static __device__ __forceinline__ float wave_max(float v) {
  v = fmaxf(v, __shfl_xor(v, 32)); v = fmaxf(v, __shfl_xor(v, 16)); v = fmaxf(v, __shfl_xor(v, 8));
  v = fmaxf(v, __shfl_xor(v, 4));  v = fmaxf(v, __shfl_xor(v, 2));  v = fmaxf(v, __shfl_xor(v, 1));
  return v;
}

// ---------------- build V (and V^T per b) ----------------
// V[(t*B+b)*128 + d] = [conc_mean(64) | prob_emb(64)]
__global__ void build_v(const int* __restrict__ prob_id, const int* __restrict__ skills,
                        const float* __restrict__ concept_emb, const float* __restrict__ prob_emb,
                        float* __restrict__ V, float* __restrict__ VT) {
  int tb = blockIdx.x; int t = tb >> 6, b = tb & 63; int d = threadIdx.x;
  int pid = prob_id[tb];
  float pr = pid ? prob_emb[(pid - 1) * 64 + d] : 0.0f;
  int cnt = 0; float sum = 0.0f;
#pragma unroll
  for (int c = 0; c < 4; ++c) {
    int sk = skills[tb * 4 + c];
    if (sk) { ++cnt; sum += concept_emb[(sk - 1) * 64 + d]; }
  }
  float mean = sum / (float)(cnt ? cnt : 1);
  V[tb * 128 + d] = mean;
  V[tb * 128 + 64 + d] = pr;
  VT[b * 16384 + d * 128 + t] = mean;
  VT[b * 16384 + (64 + d) * 128 + t] = pr;
}

// ---------------- generic fp32 GEMM ----------------
// C = scale*(A@B) + bias ; M,N multiples of 64, K multiple of 32. batched via blockIdx.z.
__global__ __launch_bounds__(256) void gemm_f32(
    const float* __restrict__ A, const float* __restrict__ B, float* __restrict__ C,
    const float* __restrict__ bias, int M, int N, int K,
    int lda, int ldb, int ldc, long sA, long sB, long sC, float scale) {
  __shared__ __align__(16) float As[64 * 36];
  __shared__ __align__(16) float Bs[32 * 64];
  const float* Ab = A + (long)blockIdx.z * sA;
  const float* Bb = B + (long)blockIdx.z * sB;
  float* Cb = C + (long)blockIdx.z * sC;
  int m0 = blockIdx.y * 64, n0 = blockIdx.x * 64;
  int tid = threadIdx.x;
  int ti = tid & 15, tj = tid >> 4;
  float acc[4][4] = {};
  for (int kc = 0; kc < K; kc += 32) {
#pragma unroll
    for (int p = 0; p < 2; ++p) {
      int q = tid + 256 * p;
      int row = q >> 3, kq = q & 7;
      *(float4*)&As[row * 36 + 4 * kq] = *(const float4*)&Ab[(size_t)(m0 + row) * lda + kc + 4 * kq];
    }
#pragma unroll
    for (int p = 0; p < 2; ++p) {
      int q = tid + 256 * p;
      int k = q >> 4, nq = q & 15;
      *(float4*)&Bs[k * 64 + 4 * nq] = *(const float4*)&Bb[(size_t)(kc + k) * ldb + n0 + 4 * nq];
    }
    __syncthreads();
#pragma unroll
    for (int k4 = 0; k4 < 8; ++k4) {
      float4 av[4], bv[4];
#pragma unroll
      for (int m = 0; m < 4; ++m) av[m] = *(const float4*)&As[(ti + 16 * m) * 36 + 4 * k4];
#pragma unroll
      for (int kk = 0; kk < 4; ++kk) bv[kk] = *(const float4*)&Bs[(4 * k4 + kk) * 64 + 4 * tj];
#pragma unroll
      for (int m = 0; m < 4; ++m) {
        const float* ap = (const float*)&av[m];
#pragma unroll
        for (int kk = 0; kk < 4; ++kk) {
          float a = ap[kk];
          acc[m][0] += a * bv[kk].x; acc[m][1] += a * bv[kk].y;
          acc[m][2] += a * bv[kk].z; acc[m][3] += a * bv[kk].w;
        }
      }
    }
    __syncthreads();
  }
  float4 bq = make_float4(0.f, 0.f, 0.f, 0.f);
  if (bias) bq = *(const float4*)&bias[n0 + 4 * tj];
#pragma unroll
  for (int m = 0; m < 4; ++m) {
    int row = m0 + ti + 16 * m;
    float4 o;
    o.x = acc[m][0] * scale + bq.x; o.y = acc[m][1] * scale + bq.y;
    o.z = acc[m][2] * scale + bq.z; o.w = acc[m][3] * scale + bq.w;
    *(float4*)&Cb[(size_t)row * ldc + n0 + 4 * tj] = o;
  }
}

// ---------------- small weight folds (needs M12) ----------------
__global__ __launch_bounds__(256) void k_small(
    const float* __restrict__ W_batch, const float* __restrict__ W_bg, const float* __restrict__ b_bg,
    const float* __restrict__ W_bgint, const float* __restrict__ b_bgint,
    const float* __restrict__ W_hisint, const float* __restrict__ b_hisint,
    const float* __restrict__ W_ih, const float* __restrict__ b_ih, const float* __restrict__ b_inmap,
    const float* __restrict__ W_pred, const float* __restrict__ b_pred, const float* __restrict__ dir_w,
    const float* __restrict__ M12, float* __restrict__ B1, float* __restrict__ Hmix,
    float* __restrict__ WgT, float* __restrict__ WBvcat, float* __restrict__ Bgxv,
    float* __restrict__ c4, float* __restrict__ cgx, float* __restrict__ uh,
    float* __restrict__ bgp, float* __restrict__ c0, float* __restrict__ dwv) {
  int idx = blockIdx.x * 256 + threadIdx.x;
  const int R0 = 49152, R1 = 86016, R2 = 122880, R3 = 147456, R4 = 196608,
            R5 = 229376, R6 = 278528, R7 = 278784, R8 = 278976, R9 = 279104,
            R10 = 279488, R11 = 279489, R12 = 279491;
  if (idx < R0) { // B1 P4 section: WP4[h][k][i]
    int k = idx >> 8, n = idx & 255; int h = n >> 6, i = n & 63;
    float s = 0.f;
    for (int d = 0; d < 64; ++d) s += W_bg[h * 12288 + k * 64 + d] * W_batch[h * 12288 + i * 64 + d];
    B1[k * 640 + n] = s;
  } else if (idx < R1) { // Wmix top
    int r = idx - R0; int k = r / 192, c = r - k * 192;
    float s = 0.f;
    for (int j = 0; j < 384; ++j) s += W_bgint[k * 384 + j] * M12[j * 192 + c];
    B1[k * 640 + 256 + c] = s;
  } else if (idx < R2) { // Wmix bottom
    int r = idx - R1; int k = r / 192, c = r - k * 192;
    float s = 0.f;
    for (int j = 0; j < 384; ++j) s += W_bgint[(192 + k) * 384 + j] * M12[j * 192 + c];
    B1[k * 640 + 448 + c] = s;
  } else if (idx < R3) { // Hmix
    int r = idx - R2; int i = r / 192, c = r - i * 192;
    float s = 0.f;
    for (int j = 0; j < 384; ++j) s += W_hisint[i * 384 + j] * M12[j * 192 + c];
    Hmix[i * 192 + c] = s;
  } else if (idx < R4) { // WgT[h][d][k] = W_bg[h][k][d]
    int r = idx - R3; int h = r / 12288; int rem = r - h * 12288; int d = rem / 192, k = rem - d * 192;
    WgT[r] = W_bg[h * 12288 + k * 64 + d];
  } else if (idx < R5) { // WBvcat[i][h*64+d] = W_batch[h][64+i][d]
    int r = idx - R4; int i = r >> 8, n = r & 255; int h = n >> 6, d = n & 63;
    WBvcat[r] = W_batch[h * 12288 + (64 + i) * 64 + d];
  } else if (idx < R6) { // Bgxv
    int r = idx - R5; int i = r / 384, c = r - i * 384;
    Bgxv[r] = (c < 192) ? M12[(384 + i) * 192 + c] : M12[(512 + i) * 192 + (c - 192)];
  } else if (idx < R7) { // c4[n] = WBh[h]@b_bg[h]
    int n = idx - R6; int h = n >> 6, i = n & 63;
    float s = 0.f;
    for (int d = 0; d < 64; ++d) s += W_batch[h * 12288 + i * 64 + d] * b_bg[h * 64 + d];
    c4[n] = s;
  } else if (idx < R8) { // cgx_total
    int c = idx - R7;
    float e0 = __expf(dir_w[0]), e1 = __expf(dir_w[1]);
    float dw0 = e0 / (e0 + e1), dw1 = e1 / (e0 + e1);
    float s = b_ih[c];
    for (int i = 0; i < 256; ++i) s += b_inmap[i] * W_ih[i * 192 + c];
    for (int k = 0; k < 384; ++k) s += (dw0 * b_bgint[k] + dw1 * b_hisint[k]) * M12[k * 192 + c];
    cgx[c] = s;
  } else if (idx < R9) { // uh
    int i = idx - R8;
    float s = 0.f;
    for (int j = 0; j < 384; ++j) s += W_hisint[i * 384 + j] * W_pred[j];
    uh[i] = s;
  } else if (idx < R10) { // bgp
    int k = idx - R9;
    float s = 0.f;
    for (int j = 0; j < 384; ++j) s += W_bgint[k * 384 + j] * W_pred[j];
    bgp[k] = s;
  } else if (idx < R11) { // c0
    float e0 = __expf(dir_w[0]), e1 = __expf(dir_w[1]);
    float dw0 = e0 / (e0 + e1), dw1 = e1 / (e0 + e1);
    float s = b_pred[0];
    for (int k = 0; k < 384; ++k) s += (dw0 * b_bgint[k] + dw1 * b_hisint[k]) * W_pred[k];
    c0[0] = s;
  } else if (idx < R12) { // dwv
    float e0 = __expf(dir_w[0]), e1 = __expf(dir_w[1]);
    dwv[idx - R11] = (idx == R11) ? e0 / (e0 + e1) : e1 / (e0 + e1);
  }
}

// ---------------- big gather-GEMM: P4s/Cg ----------------
// rows = items (t,b,s); A = all_hv (gathered); B = B1 (192 x 640)
__global__ __launch_bounds__(256) void big_gemm(
    const int* __restrict__ bg_index, const int* __restrict__ mem_prob_ids,
    const int* __restrict__ mem_resp, const int* __restrict__ mem_concepts,
    const float* __restrict__ states_mem, const float* __restrict__ concept_emb,
    const float* __restrict__ prob_emb, const float* __restrict__ B1, const float* __restrict__ c4,
    float* __restrict__ P4s, float* __restrict__ Cg) {
  int mt = blockIdx.x;   // 640 row-tiles of 128
  int nt = blockIdx.y;   // 5 col-tiles of 128
  __shared__ __align__(16) float As[128 * 36];
  __shared__ __align__(16) float Bs[32 * 132];
  __shared__ int bgi_l[128]; __shared__ int rf_l[128]; __shared__ int pid_l[128];
  __shared__ int skl_l[128][4]; __shared__ float inv_l[128];
  __shared__ float c4_l[128];
  int tid = threadIdx.x;
  int n0 = nt * 128;
  if (tid < 128) {
    int item = mt * 128 + tid;
    int t = item / 640; int rem = item - t * 640; int b = rem / 10; int s = rem - b * 10;
    int g = bg_index[(t * 64 + b) * 20 + s];
    bgi_l[tid] = g;
    rf_l[tid] = mem_resp[g];
    pid_l[tid] = mem_prob_ids[g];
    int cnt = 0;
#pragma unroll
    for (int c = 0; c < 4; ++c) { int sk = mem_concepts[g * 4 + c]; skl_l[tid][c] = sk; cnt += (sk != 0); }
    inv_l[tid] = 1.0f / (float)(cnt ? cnt : 1);
    if (n0 + tid < 256) c4_l[tid] = c4[n0 + tid];
  }
  __syncthreads();
  float acc[8][8] = {};
  int ti = tid & 15, tj = tid >> 4;
  for (int kc = 0; kc < 6; ++kc) {
    int sec = kc >> 1, half = (kc & 1) * 32;
    { // gather A chunk (128 rows x 32 k)
      int dd = tid & 31, r8 = tid >> 5;
      for (int rp = 0; rp < 16; ++rp) {
        int row = rp * 8 + r8;
        int d = half + dd;
        float v;
        if (sec == 0) {
          v = states_mem[bgi_l[row] * 64 + d];
        } else if (sec == 1) {
          float sum = 0.f;
#pragma unroll
          for (int c = 0; c < 4; ++c) { int sk = skl_l[row][c]; if (sk) sum += concept_emb[(sk - 1) * 64 + d]; }
          v = sum * inv_l[row];
        } else {
          int pid = pid_l[row];
          v = pid ? prob_emb[(pid - 1) * 64 + d] : 0.0f;
        }
        As[row * 36 + dd] = v;
      }
    }
    { // load B chunk (32 k x 128 n)
      int k = tid >> 3, nq = tid & 7;
#pragma unroll
      for (int d2 = 0; d2 < 4; ++d2) {
        int n = 4 * nq + 32 * d2;
        *(float4*)&Bs[k * 132 + n] = *(const float4*)&B1[(kc * 32 + k) * 640 + n0 + n];
      }
    }
    __syncthreads();
#pragma unroll
    for (int k4 = 0; k4 < 8; ++k4) {
      float4 av[8], bv0[4], bv1[4];
#pragma unroll
      for (int m = 0; m < 8; ++m) av[m] = *(const float4*)&As[(ti + 16 * m) * 36 + 4 * k4];
#pragma unroll
      for (int kk = 0; kk < 4; ++kk) {
        bv0[kk] = *(const float4*)&Bs[(4 * k4 + kk) * 132 + 4 * tj];
        bv1[kk] = *(const float4*)&Bs[(4 * k4 + kk) * 132 + 64 + 4 * tj];
      }
#pragma unroll
      for (int m = 0; m < 8; ++m) {
        const float* ap = (const float*)&av[m];
#pragma unroll
        for (int kk = 0; kk < 4; ++kk) {
          float a = ap[kk];
          acc[m][0] += a * bv0[kk].x; acc[m][1] += a * bv0[kk].y;
          acc[m][2] += a * bv0[kk].z; acc[m][3] += a * bv0[kk].w;
          acc[m][4] += a * bv1[kk].x; acc[m][5] += a * bv1[kk].y;
          acc[m][6] += a * bv1[kk].z; acc[m][7] += a * bv1[kk].w;
        }
      }
    }
    __syncthreads();
  }
  const float invs192 = 0.07216878364870323f; // 1/sqrt(192)
#pragma unroll
  for (int m = 0; m < 8; ++m) {
    int row = ti + 16 * m; int item = mt * 128 + row;
    int rf = rf_l[row];
#pragma unroll
    for (int cb = 0; cb < 2; ++cb) {
      int nl = 4 * tj + 64 * cb;
      int n = n0 + nl;
      float4 o;
      o.x = acc[m][cb * 4 + 0]; o.y = acc[m][cb * 4 + 1];
      o.z = acc[m][cb * 4 + 2]; o.w = acc[m][cb * 4 + 3];
      if (n < 256) {
        o.x = (o.x + c4_l[nl]) * invs192; o.y = (o.y + c4_l[nl + 1]) * invs192;
        o.z = (o.z + c4_l[nl + 2]) * invs192; o.w = (o.w + c4_l[nl + 3]) * invs192;
        *(float4*)&P4s[(size_t)item * 256 + n] = o;
      } else if (n < 448) {
        if (rf) *(float4*)&Cg[(size_t)item * 192 + (n - 256)] = o;
      } else {
        if (!rf) *(float4*)&Cg[(size_t)item * 192 + (n - 448)] = o;
      }
    }
  }
}

// ---------------- per-(t,b) smalls: SQV, cbp, PROBC ----------------
__global__ __launch_bounds__(256) void k5(
    const int* __restrict__ bg_index, const int* __restrict__ mem_prob_ids,
    const int* __restrict__ mem_resp, const int* __restrict__ mem_concepts,
    const float* __restrict__ states_mem, const float* __restrict__ concept_emb,
    const float* __restrict__ prob_emb, const float* __restrict__ RQ, const float* __restrict__ QV,
    const float* __restrict__ b_bg, const float* __restrict__ bgp, const float* __restrict__ V,
    const float* __restrict__ W_pred, const float* __restrict__ c0,
    float* __restrict__ SQVb, float* __restrict__ cbp, float* __restrict__ PROBC) {
  int tb = blockIdx.x;
  int tid = threadIdx.x;
  int lane = tid & 63, wv = tid >> 6;
  __shared__ float ahv[10 * 196];
  __shared__ float rql[4 * 196];
  __shared__ float bgpl[384];
  __shared__ int bgi_l[10]; __shared__ int rf_s[10];
  __shared__ float cqb[4];
  if (tid < 10) { int g = bg_index[tb * 20 + tid]; bgi_l[tid] = g; rf_s[tid] = mem_resp[g]; }
  for (int i = tid; i < 384; i += 256) bgpl[i] = bgp[i];
  for (int i = tid; i < 768; i += 256) { int h = i / 192, c = i - h * 192; rql[h * 196 + c] = RQ[(size_t)tb * 768 + i]; }
  if (tid < 4) {
    float s = 0.f;
    for (int d = 0; d < 64; ++d) s += QV[tb * 256 + tid * 64 + d] * b_bg[tid * 64 + d];
    cqb[tid] = s;
  }
  __syncthreads();
  for (int s = 0; s < 10; ++s) {
    if (tid < 192) {
      int g = bgi_l[s]; float v;
      if (tid < 64) v = states_mem[g * 64 + tid];
      else if (tid < 128) {
        int d = tid - 64; float sum = 0.f; int cnt = 0;
#pragma unroll
        for (int c = 0; c < 4; ++c) { int sk = mem_concepts[g * 4 + c]; if (sk) { ++cnt; sum += concept_emb[(sk - 1) * 64 + d]; } }
        v = sum / (float)(cnt ? cnt : 1);
      } else {
        int pid = mem_prob_ids[g];
        v = pid ? prob_emb[(pid - 1) * 64 + (tid - 128)] : 0.0f;
      }
      ahv[s * 196 + tid] = v;
    }
  }
  __syncthreads();
  const float invs192 = 0.07216878364870323f;
  for (int q = 0; q < 10; ++q) { // SQV pairs: h = wv, s = q
    float v = ahv[q * 196 + lane] * rql[wv * 196 + lane]
            + ahv[q * 196 + 64 + lane] * rql[wv * 196 + 64 + lane]
            + ahv[q * 196 + 128 + lane] * rql[wv * 196 + 128 + lane];
    v = wave_sum(v);
    if (lane == 0) SQVb[tb * 40 + wv * 10 + q] = (v + cqb[wv]) * invs192;
  }
  if (wv == 0) {
    for (int q = 0; q < 10; ++q) {
      int off = rf_s[q] ? 0 : 192;
      float v = ahv[q * 196 + lane] * bgpl[off + lane]
              + ahv[q * 196 + 64 + lane] * bgpl[off + 64 + lane]
              + ahv[q * 196 + 128 + lane] * bgpl[off + 128 + lane];
      v = wave_sum(v);
      if (lane == 0) cbp[tb * 10 + q] = v;
    }
  }
  if (wv == 1) {
    float v = V[tb * 128 + lane] * W_pred[384 + lane] + V[tb * 128 + 64 + lane] * W_pred[448 + lane];
    v = wave_sum(v);
    if (lane == 0) PROBC[tb] = v + c0[0];
  }
}

// ---------------- sequential recurrence: one block per b ----------------
__global__ __launch_bounds__(512) void seq_kernel(
    const int* __restrict__ response, const float* __restrict__ S, const float* __restrict__ P4s,
    const float* __restrict__ SQVb, const float* __restrict__ Cg, const float* __restrict__ cbp,
    const float* __restrict__ GXV, const float* __restrict__ PROBC, const float* __restrict__ Hmix,
    const float* __restrict__ W_hh, const float* __restrict__ b_hh, const float* __restrict__ cgx,
    const float* __restrict__ uh, const float* __restrict__ W_pred, const float* __restrict__ heads_map,
    const float* __restrict__ dwv, float* __restrict__ out) {
  int b = blockIdx.x;
  int tid = threadIdx.x;
  int lane = tid & 63, wv = tid >> 6;
  int cg3 = lane * 3;
  int ig = wv;
  float hreg[16][3], wreg[8][3];
#pragma unroll
  for (int ii = 0; ii < 16; ++ii)
#pragma unroll
    for (int cc = 0; cc < 3; ++cc) hreg[ii][cc] = Hmix[(ig * 16 + ii) * 192 + cg3 + cc];
#pragma unroll
  for (int ii = 0; ii < 8; ++ii)
#pragma unroll
    for (int cc = 0; cc < 3; ++cc) wreg[ii][cc] = W_hh[(ig * 8 + ii) * 192 + cg3 + cc];
  __shared__ float h_hist[130][64];
  __shared__ float h_cur[64];
  __shared__ float rb[130];
  __shared__ float sc_l[130], p_l[130], prl[130];
  __shared__ float score_l[40], ws_l[10];
  __shared__ float hisA[128];
  __shared__ float red8[8][192];
  __shared__ float redW[8][192];
  __shared__ float gx_l[192], gh_l[192];
  __shared__ float cgx_l[192], uh_l[128], wph_l[64], hm_l[4];
  __shared__ float smax, ssum, pbg, phis, hwp;
  if (tid < 64) { h_cur[tid] = 0.f; h_hist[0][tid] = 0.f; wph_l[tid] = W_pred[512 + tid]; }
  if (tid == 0) rb[0] = 0.f;
  if (tid < 192) cgx_l[tid] = cgx[tid];
  if (tid >= 256 && tid < 384) uh_l[tid - 256] = uh[tid - 256];
  if (tid >= 384 && tid < 388) hm_l[tid - 384] = heads_map[tid - 384];
  float dw0 = dwv[0], dw1 = dwv[1];
  __syncthreads();
  for (int t = 0; t < 128; ++t) {
    int tb = t * 64 + b;
    int resp_t = response[tb];
    // A: bg-att scores (8 waves x 5 pairs), gh partials, sc row
#pragma unroll
    for (int q = 0; q < 5; ++q) {
      int p = wv * 5 + q; int hh = p / 10, s = p - hh * 10;
      float v = h_cur[lane] * P4s[(size_t)(tb * 10 + s) * 256 + hh * 64 + lane];
      v = wave_sum(v);
      if (lane == 0) score_l[p] = v + SQVb[tb * 40 + p];
    }
    {
      float l0 = 0.f, l1 = 0.f, l2 = 0.f;
#pragma unroll
      for (int ii = 0; ii < 8; ++ii) {
        float hv = h_cur[ig * 8 + ii];
        l0 += hv * wreg[ii][0]; l1 += hv * wreg[ii][1]; l2 += hv * wreg[ii][2];
      }
      redW[ig][cg3] = l0; redW[ig][cg3 + 1] = l1; redW[ig][cg3 + 2] = l2;
    }
    for (int j = tid; j <= t; j += 512) sc_l[j] = j ? S[(b * 128 + t) * 128 + (j - 1)] : 0.f;
    __syncthreads();
    // B: head softmax; his max; gh final
    if (tid < 4) {
      float mx = -1e30f;
#pragma unroll
      for (int s = 0; s < 10; ++s) mx = fmaxf(mx, score_l[tid * 10 + s]);
      float e[10], sum = 0.f;
#pragma unroll
      for (int s = 0; s < 10; ++s) { e[s] = __expf(score_l[tid * 10 + s] - mx); sum += e[s]; }
      float inv = 1.f / sum;
#pragma unroll
      for (int s = 0; s < 10; ++s) score_l[tid * 10 + s] = e[s] * inv;
    }
    if (wv == 1) {
      float m = -1e30f;
      for (int j = lane; j <= t; j += 64) m = fmaxf(m, sc_l[j]);
      m = wave_max(m);
      if (lane == 0) smax = m;
    }
    if (tid >= 256 && tid < 448) {
      int c = tid - 256;
      float g = 0.f;
#pragma unroll
      for (int gg = 0; gg < 8; ++gg) g += redW[gg][c];
      gh_l[c] = g + b_hh[c];
    }
    __syncthreads();
    // C: ws; exp p
    if (tid < 10) {
      float wsum = 0.f;
#pragma unroll
      for (int hh = 0; hh < 4; ++hh) wsum += hm_l[hh] * score_l[hh * 10 + tid];
      ws_l[tid] = wsum;
    }
    {
      float m = smax;
      for (int j = tid; j <= t; j += 512) {
        float e = __expf(sc_l[j] - m);
        p_l[j] = e; prl[j] = e * rb[j];
      }
    }
    __syncthreads();
    // D: ssum; gx partial (bg + GXV + cgx); pbg; hwp
    if (wv == 0) {
      float sm = 0.f;
      for (int j = lane; j <= t; j += 64) sm += p_l[j];
      sm = wave_sum(sm);
      if (lane == 0) ssum = sm;
    }
    if (tid >= 64 && tid < 256) {
      int c = tid - 64;
      float gbg = 0.f;
#pragma unroll
      for (int s = 0; s < 10; ++s) gbg += ws_l[s] * Cg[(size_t)(tb * 10 + s) * 192 + c];
      int off = resp_t ? 0 : 192;
      gx_l[c] = dw0 * gbg + GXV[(size_t)tb * 384 + off + c] + cgx_l[c];
    }
    if (wv == 6) {
      float v = (lane < 10) ? ws_l[lane] * cbp[tb * 10 + lane] : 0.f;
      v = wave_sum(v);
      if (lane == 0) pbg = v;
    }
    if (wv == 7) {
      float v = h_cur[lane] * wph_l[lane];
      v = wave_sum(v);
      if (lane == 0) hwp = v;
    }
    __syncthreads();
    // E: history attention sums
    {
      int d = tid & 63, jg = tid >> 6;
      float aR = 0.f, aA = 0.f;
      for (int j = jg; j <= t; j += 8) {
        float hv = h_hist[j][d];
        aR += prl[j] * hv; aA += p_l[j] * hv;
      }
      red8[jg][d] = aR; red8[jg][64 + d] = aA;
    }
    __syncthreads();
    // F: hisA
    if (tid < 64) {
      float sR = 0.f, sA = 0.f;
#pragma unroll
      for (int g = 0; g < 8; ++g) { sR += red8[g][tid]; sA += red8[g][64 + tid]; }
      float inv = 1.f / ssum;
      hisA[tid] = sR * inv; hisA[64 + tid] = (sA - sR) * inv;
    }
    __syncthreads();
    // G: his@Hmix partials (register weights); phis
    {
      float l0 = 0.f, l1 = 0.f, l2 = 0.f;
#pragma unroll
      for (int ii = 0; ii < 16; ++ii) {
        float hv = hisA[ig * 16 + ii];
        l0 += hv * hreg[ii][0]; l1 += hv * hreg[ii][1]; l2 += hv * hreg[ii][2];
      }
      redW[ig][cg3] = l0; redW[ig][cg3 + 1] = l1; redW[ig][cg3 + 2] = l2;
    }
    if (wv == 1) {
      float v = hisA[lane] * uh_l[lane] + hisA[64 + lane] * uh_l[64 + lane];
      v = wave_sum(v);
      if (lane == 0) phis = v;
    }
    __syncthreads();
    // H: gx final; prob
    if (tid < 192) {
      float gxh = 0.f;
#pragma unroll
      for (int g = 0; g < 8; ++g) gxh += redW[g][tid];
      gx_l[tid] += dw1 * gxh;
    }
    if (tid == 256) out[b * 128 + t] = dw0 * pbg + dw1 * phis + hwp + PROBC[tb];
    __syncthreads();
    // I: GRU update
    if (tid < 64) {
      float xr = gx_l[tid], xz = gx_l[64 + tid], xn = gx_l[128 + tid];
      float hr = gh_l[tid], hz = gh_l[64 + tid], hn = gh_l[128 + tid];
      float r = 1.f / (1.f + __expf(-(xr + hr)));
      float z = 1.f / (1.f + __expf(-(xz + hz)));
      float n = tanhf(xn + r * hn);
      float hnew = (1.f - z) * n + z * h_cur[tid];
      h_cur[tid] = hnew; h_hist[t + 1][tid] = hnew;
    }
    if (tid == 64) rb[t + 1] = (float)resp_t;
    __syncthreads();
  }
}

// ---------------- launch ----------------
extern "C" void kernel_launch(void* const* d_in, const int* in_sizes, int n_in,
                              void* d_out, int out_size, void* d_ws, size_t ws_size,
                              hipStream_t stream) {
  const int* prob_id      = (const int*)d_in[0];
  const int* skills       = (const int*)d_in[1];
  const int* response     = (const int*)d_in[2];
  const int* bg_index     = (const int*)d_in[3];
  const int* mem_prob_ids = (const int*)d_in[4];
  const int* mem_resp     = (const int*)d_in[5];
  const int* mem_concepts = (const int*)d_in[6];
  const float* states_mem  = (const float*)d_in[7];
  const float* concept_emb = (const float*)d_in[8];
  const float* prob_emb    = (const float*)d_in[9];
  const float* W_pred   = (const float*)d_in[10];
  const float* b_pred   = (const float*)d_in[11];
  const float* W_ih     = (const float*)d_in[12];
  const float* W_hh     = (const float*)d_in[13];
  const float* b_ih     = (const float*)d_in[14];
  const float* b_hh     = (const float*)d_in[15];
  const float* W_batch  = (const float*)d_in[16];
  const float* b_batch  = (const float*)d_in[17];
  const float* W_bg     = (const float*)d_in[18];
  const float* b_bg     = (const float*)d_in[19];
  const float* W_bgint  = (const float*)d_in[20];
  const float* b_bgint  = (const float*)d_in[21];
  const float* W_hisint = (const float*)d_in[22];
  const float* b_hisint = (const float*)d_in[23];
  const float* W_inmap  = (const float*)d_in[24];
  const float* b_inmap  = (const float*)d_in[25];
  const float* dir_w    = (const float*)d_in[26];
  const float* heads_map= (const float*)d_in[27];
  float* out = (float*)d_out;

  float* w = (float*)d_ws;
  size_t off = 0;
  auto alloc = [&](size_t n) { float* p = w + off; off += n; return p; };
  float* M12    = alloc(640 * 192);
  float* B1     = alloc(192 * 640);
  float* Hmix   = alloc(128 * 192);
  float* WgT    = alloc(4 * 192 * 64);
  float* WBvcat = alloc(128 * 256);
  float* Bgxv   = alloc(128 * 384);
  float* c4     = alloc(256);
  float* cgx    = alloc(192);
  float* uh     = alloc(128);
  float* bgp    = alloc(384);
  float* c0     = alloc(1);
  float* dwv    = alloc(2);
  float* V      = alloc((size_t)8192 * 128);
  float* VT     = alloc((size_t)64 * 128 * 128);
  float* QV     = alloc((size_t)8192 * 256);
  float* RQ     = alloc((size_t)8192 * 768);
  float* GXV    = alloc((size_t)8192 * 384);
  float* S      = alloc((size_t)64 * 128 * 128);
  float* P4s    = alloc((size_t)NITEM * 256);
  float* Cg     = alloc((size_t)NITEM * 192);
  float* SQVb   = alloc((size_t)8192 * 40);
  float* cbp    = alloc((size_t)NITEM);
  float* PROBC  = alloc(8192);
  (void)ws_size; (void)in_sizes; (void)n_in; (void)out_size;

  build_v<<<8192, 64, 0, stream>>>(prob_id, skills, concept_emb, prob_emb, V, VT);
  // M12 = W_inmap @ W_ih  (640x256 @ 256x192)
  gemm_f32<<<dim3(3, 10, 1), 256, 0, stream>>>(W_inmap, W_ih, M12, nullptr,
      640, 192, 256, 256, 192, 192, 0, 0, 0, 1.0f);
  k_small<<<1092, 256, 0, stream>>>(W_batch, W_bg, b_bg, W_bgint, b_bgint, W_hisint, b_hisint,
      W_ih, b_ih, b_inmap, W_pred, b_pred, dir_w, M12, B1, Hmix, WgT, WBvcat, Bgxv,
      c4, cgx, uh, bgp, c0, dwv);
  // QV = V @ WBvcat + b_batch  (8192x128 @ 128x256)
  gemm_f32<<<dim3(4, 128, 1), 256, 0, stream>>>(V, WBvcat, QV, b_batch,
      8192, 256, 128, 128, 256, 256, 0, 0, 0, 1.0f);
  // RQ[h] = QV_h @ WgT[h]  (8192x64 @ 64x192)
  for (int h = 0; h < 4; ++h)
    gemm_f32<<<dim3(3, 128, 1), 256, 0, stream>>>(QV + h * 64, WgT + h * 12288, RQ + h * 192, nullptr,
        8192, 192, 64, 256, 192, 768, 0, 0, 0, 1.0f);
  // GXV = V @ Bgxv  (8192x128 @ 128x384)
  gemm_f32<<<dim3(6, 128, 1), 256, 0, stream>>>(V, Bgxv, GXV, nullptr,
      8192, 384, 128, 128, 384, 384, 0, 0, 0, 1.0f);
  // S[b] = (V_b @ V_b^T)/sqrt(128) batched over b
  gemm_f32<<<dim3(2, 2, 64), 256, 0, stream>>>(V, VT, S, nullptr,
      128, 128, 128, 8192, 128, 128, 128, 16384, 16384, 0.08838834764831845f);
  big_gemm<<<dim3(640, 5, 1), 256, 0, stream>>>(bg_index, mem_prob_ids, mem_resp, mem_concepts,
      states_mem, concept_emb, prob_emb, B1, c4, P4s, Cg);
  k5<<<8192, 256, 0, stream>>>(bg_index, mem_prob_ids, mem_resp, mem_concepts,
      states_mem, concept_emb, prob_emb, RQ, QV, b_bg, bgp, V, W_pred, c0, SQVb, cbp, PROBC);
  seq_kernel<<<64, 512, 0, stream>>>(response, S, P4s, SQVb, Cg, cbp, GXV, PROBC,
      Hmix, W_hh, b_hh, cgx, uh, W_pred, heads_map, dwv, out);
}

// Round 2
// 1228.868 us; speedup vs baseline: 1.2943x; 1.2943x over previous
//
#include <hip/hip_runtime.h>
#include <hip/hip_bf16.h>

// ---------------- constants ----------------
#define TT 128
#define BB 64
#define DD 64
#define RR 20
#define SEE 10
#define HH 4
#define CC 4
#define NITEM (TT*BB*SEE)     // 81920
static __device__ __forceinline__ float wave_sum(float v) {
  v += __shfl_xor(v, 32); v += __shfl_xor(v, 16); v += __shfl_xor(v, 8);
  v += __shfl_xor(v, 4);  v += __shfl_xor(v, 2);  v += __shfl_xor(v, 1);
  return v;
}
static __device__ __forceinline__ float wave_max(float v) {
  v = fmaxf(v, __shfl_xor(v, 32)); v = fmaxf(v, __shfl_xor(v, 16)); v = fmaxf(v, __shfl_xor(v, 8));
  v = fmaxf(v, __shfl_xor(v, 4));  v = fmaxf(v, __shfl_xor(v, 2));  v = fmaxf(v, __shfl_xor(v, 1));
  return v;
}

// ---------------- build V (and V^T per b) ----------------
__global__ void build_v(const int* __restrict__ prob_id, const int* __restrict__ skills,
                        const float* __restrict__ concept_emb, const float* __restrict__ prob_emb,
                        float* __restrict__ V, float* __restrict__ VT) {
  int tb = blockIdx.x; int t = tb >> 6, b = tb & 63; int d = threadIdx.x;
  int pid = prob_id[tb];
  float pr = pid ? prob_emb[(pid - 1) * 64 + d] : 0.0f;
  int cnt = 0; float sum = 0.0f;
#pragma unroll
  for (int c = 0; c < 4; ++c) {
    int sk = skills[tb * 4 + c];
    if (sk) { ++cnt; sum += concept_emb[(sk - 1) * 64 + d]; }
  }
  float mean = sum / (float)(cnt ? cnt : 1);
  V[tb * 128 + d] = mean;
  V[tb * 128 + 64 + d] = pr;
  VT[b * 16384 + d * 128 + t] = mean;
  VT[b * 16384 + (64 + d) * 128 + t] = pr;
}

// ---------------- generic fp32 GEMM ----------------
__global__ __launch_bounds__(256) void gemm_f32(
    const float* __restrict__ A, const float* __restrict__ B, float* __restrict__ C,
    const float* __restrict__ bias, int M, int N, int K,
    int lda, int ldb, int ldc, long sA, long sB, long sC, float scale) {
  __shared__ __align__(16) float As[64 * 36];
  __shared__ __align__(16) float Bs[32 * 64];
  const float* Ab = A + (long)blockIdx.z * sA;
  const float* Bb = B + (long)blockIdx.z * sB;
  float* Cb = C + (long)blockIdx.z * sC;
  int m0 = blockIdx.y * 64, n0 = blockIdx.x * 64;
  int tid = threadIdx.x;
  int ti = tid & 15, tj = tid >> 4;
  float acc[4][4] = {};
  for (int kc = 0; kc < K; kc += 32) {
#pragma unroll
    for (int p = 0; p < 2; ++p) {
      int q = tid + 256 * p;
      int row = q >> 3, kq = q & 7;
      *(float4*)&As[row * 36 + 4 * kq] = *(const float4*)&Ab[(size_t)(m0 + row) * lda + kc + 4 * kq];
    }
#pragma unroll
    for (int p = 0; p < 2; ++p) {
      int q = tid + 256 * p;
      int k = q >> 4, nq = q & 15;
      *(float4*)&Bs[k * 64 + 4 * nq] = *(const float4*)&Bb[(size_t)(kc + k) * ldb + n0 + 4 * nq];
    }
    __syncthreads();
#pragma unroll
    for (int k4 = 0; k4 < 8; ++k4) {
      float4 av[4], bv[4];
#pragma unroll
      for (int m = 0; m < 4; ++m) av[m] = *(const float4*)&As[(ti + 16 * m) * 36 + 4 * k4];
#pragma unroll
      for (int kk = 0; kk < 4; ++kk) bv[kk] = *(const float4*)&Bs[(4 * k4 + kk) * 64 + 4 * tj];
#pragma unroll
      for (int m = 0; m < 4; ++m) {
        const float* ap = (const float*)&av[m];
#pragma unroll
        for (int kk = 0; kk < 4; ++kk) {
          float a = ap[kk];
          acc[m][0] += a * bv[kk].x; acc[m][1] += a * bv[kk].y;
          acc[m][2] += a * bv[kk].z; acc[m][3] += a * bv[kk].w;
        }
      }
    }
    __syncthreads();
  }
  float4 bq = make_float4(0.f, 0.f, 0.f, 0.f);
  if (bias) bq = *(const float4*)&bias[n0 + 4 * tj];
#pragma unroll
  for (int m = 0; m < 4; ++m) {
    int row = m0 + ti + 16 * m;
    float4 o;
    o.x = acc[m][0] * scale + bq.x; o.y = acc[m][1] * scale + bq.y;
    o.z = acc[m][2] * scale + bq.z; o.w = acc[m][3] * scale + bq.w;
    *(float4*)&Cb[(size_t)row * ldc + n0 + 4 * tj] = o;
  }
}

// ---------------- small weight folds (needs M12) ----------------
__global__ __launch_bounds__(256) void k_small(
    const float* __restrict__ W_batch, const float* __restrict__ W_bg, const float* __restrict__ b_bg,
    const float* __restrict__ W_bgint, const float* __restrict__ b_bgint,
    const float* __restrict__ W_hisint, const float* __restrict__ b_hisint,
    const float* __restrict__ W_ih, const float* __restrict__ b_ih, const float* __restrict__ b_inmap,
    const float* __restrict__ W_pred, const float* __restrict__ b_pred, const float* __restrict__ dir_w,
    const float* __restrict__ M12, float* __restrict__ B1, float* __restrict__ Hmix,
    float* __restrict__ WgT, float* __restrict__ WBvcat, float* __restrict__ Bgxv,
    float* __restrict__ c4, float* __restrict__ cgx, float* __restrict__ uh,
    float* __restrict__ bgp, float* __restrict__ c0, float* __restrict__ dwv) {
  int idx = blockIdx.x * 256 + threadIdx.x;
  const int R0 = 49152, R1 = 86016, R2 = 122880, R3 = 147456, R4 = 196608,
            R5 = 229376, R6 = 278528, R7 = 278784, R8 = 278976, R9 = 279104,
            R10 = 279488, R11 = 279489, R12 = 279491;
  if (idx < R0) {
    int k = idx >> 8, n = idx & 255; int h = n >> 6, i = n & 63;
    float s = 0.f;
    for (int d = 0; d < 64; ++d) s += W_bg[h * 12288 + k * 64 + d] * W_batch[h * 12288 + i * 64 + d];
    B1[k * 640 + n] = s;
  } else if (idx < R1) {
    int r = idx - R0; int k = r / 192, c = r - k * 192;
    float s = 0.f;
    for (int j = 0; j < 384; ++j) s += W_bgint[k * 384 + j] * M12[j * 192 + c];
    B1[k * 640 + 256 + c] = s;
  } else if (idx < R2) {
    int r = idx - R1; int k = r / 192, c = r - k * 192;
    float s = 0.f;
    for (int j = 0; j < 384; ++j) s += W_bgint[(192 + k) * 384 + j] * M12[j * 192 + c];
    B1[k * 640 + 448 + c] = s;
  } else if (idx < R3) {
    int r = idx - R2; int i = r / 192, c = r - i * 192;
    float s = 0.f;
    for (int j = 0; j < 384; ++j) s += W_hisint[i * 384 + j] * M12[j * 192 + c];
    Hmix[i * 192 + c] = s;
  } else if (idx < R4) {
    int r = idx - R3; int h = r / 12288; int rem = r - h * 12288; int d = rem / 192, k = rem - d * 192;
    WgT[r] = W_bg[h * 12288 + k * 64 + d];
  } else if (idx < R5) {
    int r = idx - R4; int i = r >> 8, n = r & 255; int h = n >> 6, d = n & 63;
    WBvcat[r] = W_batch[h * 12288 + (64 + i) * 64 + d];
  } else if (idx < R6) {
    int r = idx - R5; int i = r / 384, c = r - i * 384;
    Bgxv[r] = (c < 192) ? M12[(384 + i) * 192 + c] : M12[(512 + i) * 192 + (c - 192)];
  } else if (idx < R7) {
    int n = idx - R6; int h = n >> 6, i = n & 63;
    float s = 0.f;
    for (int d = 0; d < 64; ++d) s += W_batch[h * 12288 + i * 64 + d] * b_bg[h * 64 + d];
    c4[n] = s;
  } else if (idx < R8) {
    int c = idx - R7;
    float e0 = __expf(dir_w[0]), e1 = __expf(dir_w[1]);
    float dw0 = e0 / (e0 + e1), dw1 = e1 / (e0 + e1);
    float s = b_ih[c];
    for (int i = 0; i < 256; ++i) s += b_inmap[i] * W_ih[i * 192 + c];
    for (int k = 0; k < 384; ++k) s += (dw0 * b_bgint[k] + dw1 * b_hisint[k]) * M12[k * 192 + c];
    cgx[c] = s;
  } else if (idx < R9) {
    int i = idx - R8;
    float s = 0.f;
    for (int j = 0; j < 384; ++j) s += W_hisint[i * 384 + j] * W_pred[j];
    uh[i] = s;
  } else if (idx < R10) {
    int k = idx - R9;
    float s = 0.f;
    for (int j = 0; j < 384; ++j) s += W_bgint[k * 384 + j] * W_pred[j];
    bgp[k] = s;
  } else if (idx < R11) {
    float e0 = __expf(dir_w[0]), e1 = __expf(dir_w[1]);
    float dw0 = e0 / (e0 + e1), dw1 = e1 / (e0 + e1);
    float s = b_pred[0];
    for (int k = 0; k < 384; ++k) s += (dw0 * b_bgint[k] + dw1 * b_hisint[k]) * W_pred[k];
    c0[0] = s;
  } else if (idx < R12) {
    float e0 = __expf(dir_w[0]), e1 = __expf(dir_w[1]);
    dwv[idx - R11] = (idx == R11) ? e0 / (e0 + e1) : e1 / (e0 + e1);
  }
}

// ---------------- big gather-GEMM: P4s/Cg ----------------
__global__ __launch_bounds__(256) void big_gemm(
    const int* __restrict__ bg_index, const int* __restrict__ mem_prob_ids,
    const int* __restrict__ mem_resp, const int* __restrict__ mem_concepts,
    const float* __restrict__ states_mem, const float* __restrict__ concept_emb,
    const float* __restrict__ prob_emb, const float* __restrict__ B1, const float* __restrict__ c4,
    float* __restrict__ P4s, float* __restrict__ Cg) {
  int mt = blockIdx.x;
  int nt = blockIdx.y;
  __shared__ __align__(16) float As[128 * 36];
  __shared__ __align__(16) float Bs[32 * 132];
  __shared__ int bgi_l[128]; __shared__ int rf_l[128]; __shared__ int pid_l[128];
  __shared__ int skl_l[128][4]; __shared__ float inv_l[128];
  __shared__ float c4_l[128];
  int tid = threadIdx.x;
  int n0 = nt * 128;
  if (tid < 128) {
    int item = mt * 128 + tid;
    int t = item / 640; int rem = item - t * 640; int b = rem / 10; int s = rem - b * 10;
    int g = bg_index[(t * 64 + b) * 20 + s];
    bgi_l[tid] = g;
    rf_l[tid] = mem_resp[g];
    pid_l[tid] = mem_prob_ids[g];
    int cnt = 0;
#pragma unroll
    for (int c = 0; c < 4; ++c) { int sk = mem_concepts[g * 4 + c]; skl_l[tid][c] = sk; cnt += (sk != 0); }
    inv_l[tid] = 1.0f / (float)(cnt ? cnt : 1);
    if (n0 + tid < 256) c4_l[tid] = c4[n0 + tid];
  }
  __syncthreads();
  float acc[8][8] = {};
  int ti = tid & 15, tj = tid >> 4;
  for (int kc = 0; kc < 6; ++kc) {
    int sec = kc >> 1, half = (kc & 1) * 32;
    {
      int dd = tid & 31, r8 = tid >> 5;
      for (int rp = 0; rp < 16; ++rp) {
        int row = rp * 8 + r8;
        int d = half + dd;
        float v;
        if (sec == 0) {
          v = states_mem[bgi_l[row] * 64 + d];
        } else if (sec == 1) {
          float sum = 0.f;
#pragma unroll
          for (int c = 0; c < 4; ++c) { int sk = skl_l[row][c]; if (sk) sum += concept_emb[(sk - 1) * 64 + d]; }
          v = sum * inv_l[row];
        } else {
          int pid = pid_l[row];
          v = pid ? prob_emb[(pid - 1) * 64 + d] : 0.0f;
        }
        As[row * 36 + dd] = v;
      }
    }
    {
      int k = tid >> 3, nq = tid & 7;
#pragma unroll
      for (int d2 = 0; d2 < 4; ++d2) {
        int n = 4 * nq + 32 * d2;
        *(float4*)&Bs[k * 132 + n] = *(const float4*)&B1[(kc * 32 + k) * 640 + n0 + n];
      }
    }
    __syncthreads();
#pragma unroll
    for (int k4 = 0; k4 < 8; ++k4) {
      float4 av[8], bv0[4], bv1[4];
#pragma unroll
      for (int m = 0; m < 8; ++m) av[m] = *(const float4*)&As[(ti + 16 * m) * 36 + 4 * k4];
#pragma unroll
      for (int kk = 0; kk < 4; ++kk) {
        bv0[kk] = *(const float4*)&Bs[(4 * k4 + kk) * 132 + 4 * tj];
        bv1[kk] = *(const float4*)&Bs[(4 * k4 + kk) * 132 + 64 + 4 * tj];
      }
#pragma unroll
      for (int m = 0; m < 8; ++m) {
        const float* ap = (const float*)&av[m];
#pragma unroll
        for (int kk = 0; kk < 4; ++kk) {
          float a = ap[kk];
          acc[m][0] += a * bv0[kk].x; acc[m][1] += a * bv0[kk].y;
          acc[m][2] += a * bv0[kk].z; acc[m][3] += a * bv0[kk].w;
          acc[m][4] += a * bv1[kk].x; acc[m][5] += a * bv1[kk].y;
          acc[m][6] += a * bv1[kk].z; acc[m][7] += a * bv1[kk].w;
        }
      }
    }
    __syncthreads();
  }
  const float invs192 = 0.07216878364870323f;
#pragma unroll
  for (int m = 0; m < 8; ++m) {
    int row = ti + 16 * m; int item = mt * 128 + row;
    int rf = rf_l[row];
#pragma unroll
    for (int cb = 0; cb < 2; ++cb) {
      int nl = 4 * tj + 64 * cb;
      int n = n0 + nl;
      float4 o;
      o.x = acc[m][cb * 4 + 0]; o.y = acc[m][cb * 4 + 1];
      o.z = acc[m][cb * 4 + 2]; o.w = acc[m][cb * 4 + 3];
      if (n < 256) {
        o.x = (o.x + c4_l[nl]) * invs192; o.y = (o.y + c4_l[nl + 1]) * invs192;
        o.z = (o.z + c4_l[nl + 2]) * invs192; o.w = (o.w + c4_l[nl + 3]) * invs192;
        *(float4*)&P4s[(size_t)item * 256 + n] = o;
      } else if (n < 448) {
        if (rf) *(float4*)&Cg[(size_t)item * 192 + (n - 256)] = o;
      } else {
        if (!rf) *(float4*)&Cg[(size_t)item * 192 + (n - 448)] = o;
      }
    }
  }
}

// ---------------- per-(t,b) smalls: SQV, cbp, PROBC ----------------
__global__ __launch_bounds__(256) void k5(
    const int* __restrict__ bg_index, const int* __restrict__ mem_prob_ids,
    const int* __restrict__ mem_resp, const int* __restrict__ mem_concepts,
    const float* __restrict__ states_mem, const float* __restrict__ concept_emb,
    const float* __restrict__ prob_emb, const float* __restrict__ RQ, const float* __restrict__ QV,
    const float* __restrict__ b_bg, const float* __restrict__ bgp, const float* __restrict__ V,
    const float* __restrict__ W_pred, const float* __restrict__ c0,
    float* __restrict__ SQVb, float* __restrict__ cbp, float* __restrict__ PROBC) {
  int tb = blockIdx.x;
  int tid = threadIdx.x;
  int lane = tid & 63, wv = tid >> 6;
  __shared__ float ahv[10 * 196];
  __shared__ float rql[4 * 196];
  __shared__ float bgpl[384];
  __shared__ int bgi_l[10]; __shared__ int rf_s[10];
  __shared__ float cqb[4];
  if (tid < 10) { int g = bg_index[tb * 20 + tid]; bgi_l[tid] = g; rf_s[tid] = mem_resp[g]; }
  for (int i = tid; i < 384; i += 256) bgpl[i] = bgp[i];
  for (int i = tid; i < 768; i += 256) { int h = i / 192, c = i - h * 192; rql[h * 196 + c] = RQ[(size_t)tb * 768 + i]; }
  if (tid < 4) {
    float s = 0.f;
    for (int d = 0; d < 64; ++d) s += QV[tb * 256 + tid * 64 + d] * b_bg[tid * 64 + d];
    cqb[tid] = s;
  }
  __syncthreads();
  for (int s = 0; s < 10; ++s) {
    if (tid < 192) {
      int g = bgi_l[s]; float v;
      if (tid < 64) v = states_mem[g * 64 + tid];
      else if (tid < 128) {
        int d = tid - 64; float sum = 0.f; int cnt = 0;
#pragma unroll
        for (int c = 0; c < 4; ++c) { int sk = mem_concepts[g * 4 + c]; if (sk) { ++cnt; sum += concept_emb[(sk - 1) * 64 + d]; } }
        v = sum / (float)(cnt ? cnt : 1);
      } else {
        int pid = mem_prob_ids[g];
        v = pid ? prob_emb[(pid - 1) * 64 + (tid - 128)] : 0.0f;
      }
      ahv[s * 196 + tid] = v;
    }
  }
  __syncthreads();
  const float invs192 = 0.07216878364870323f;
  for (int q = 0; q < 10; ++q) {
    float v = ahv[q * 196 + lane] * rql[wv * 196 + lane]
            + ahv[q * 196 + 64 + lane] * rql[wv * 196 + 64 + lane]
            + ahv[q * 196 + 128 + lane] * rql[wv * 196 + 128 + lane];
    v = wave_sum(v);
    if (lane == 0) SQVb[tb * 40 + wv * 10 + q] = (v + cqb[wv]) * invs192;
  }
  if (wv == 0) {
    for (int q = 0; q < 10; ++q) {
      int off = rf_s[q] ? 0 : 192;
      float v = ahv[q * 196 + lane] * bgpl[off + lane]
              + ahv[q * 196 + 64 + lane] * bgpl[off + 64 + lane]
              + ahv[q * 196 + 128 + lane] * bgpl[off + 128 + lane];
      v = wave_sum(v);
      if (lane == 0) cbp[tb * 10 + q] = v;
    }
  }
  if (wv == 1) {
    float v = V[tb * 128 + lane] * W_pred[384 + lane] + V[tb * 128 + 64 + lane] * W_pred[448 + lane];
    v = wave_sum(v);
    if (lane == 0) PROBC[tb] = v + c0[0];
  }
}

// ---------------- precompute history softmax weights ----------------
// PW[(b*128+t)*128 + j] = softmax_j<=t(sc)[j]; PR = PW * rb[j].
// PW may alias S (in-place): each block owns its row; loads complete (waitcnt
// before the reductions) before stores issue.
__global__ __launch_bounds__(64) void prep_pw(const float* S, const int* response,
                                              float* PW, float* PR) {
  int bt = blockIdx.x; int b = bt >> 7, t = bt & 127;
  int lane = threadIdx.x;
  size_t row = (size_t)bt * 128;
  float s0 = (lane == 0) ? 0.f : ((lane <= t) ? S[row + lane - 1] : -1e30f);
  float s1 = (lane + 64 <= t) ? S[row + lane + 63] : -1e30f;
  float m = wave_max(fmaxf(s0, s1));
  float e0 = (lane <= t) ? __expf(s0 - m) : 0.f;
  float e1 = (lane + 64 <= t) ? __expf(s1 - m) : 0.f;
  float inv = 1.f / wave_sum(e0 + e1);
  float r0 = (lane >= 1) ? (float)response[(lane - 1) * 64 + b] : 0.f;
  float r1 = (float)response[(lane + 63) * 64 + b];
  PW[row + lane] = e0 * inv;
  PW[row + 64 + lane] = e1 * inv;
  PR[row + lane] = e0 * inv * r0;
  PR[row + 64 + lane] = e1 * inv * r1;
}

// ---------------- sequential recurrence: one block per b ----------------
// 5 barrier phases/step; all global data register-prefetched one step ahead.
__global__ __launch_bounds__(512) void seq_kernel(
    const int* __restrict__ response, const float* __restrict__ P4s,
    const float* __restrict__ SQVb, const float* __restrict__ Cg,
    const float* __restrict__ GXV, const float* __restrict__ cbp,
    const float* __restrict__ PROBC, const float* __restrict__ PW,
    const float* __restrict__ PR, const float* __restrict__ Hmix,
    const float* __restrict__ W_hh, const float* __restrict__ b_hh,
    const float* __restrict__ cgx, const float* __restrict__ uh,
    const float* __restrict__ W_pred, const float* __restrict__ heads_map,
    const float* __restrict__ dwv, float* __restrict__ out) {
  int b = blockIdx.x;
  int tid = threadIdx.x;
  int lane = tid & 63, wv = tid >> 6;
  int cg3 = lane * 3;
  float hreg[16][3], wreg[8][3];
#pragma unroll
  for (int ii = 0; ii < 16; ++ii)
#pragma unroll
    for (int cc = 0; cc < 3; ++cc) hreg[ii][cc] = Hmix[(wv * 16 + ii) * 192 + cg3 + cc];
#pragma unroll
  for (int ii = 0; ii < 8; ++ii)
#pragma unroll
    for (int cc = 0; cc < 3; ++cc) wreg[ii][cc] = W_hh[(wv * 8 + ii) * 192 + cg3 + cc];
  __shared__ float h_hist[128][64];
  __shared__ __align__(16) float PWl[128];
  __shared__ __align__(16) float PRl[128];
  __shared__ float h_cur[64];
  __shared__ float score_l[40], ws_l[10];
  __shared__ float hisA[128];
  __shared__ float red8[8][128];
  __shared__ float redW[8][192];
  __shared__ float gx_l[192], gh_l[192];
  __shared__ float cgx_l[192], uh_l[128], wph_l[64], hm_l[4];
  __shared__ float sm_mx[4], sm_inv[4];
  __shared__ float phis_s, hwp_s, pbg_s;
  if (tid < 64) { h_cur[tid] = 0.f; h_hist[0][tid] = 0.f; wph_l[tid] = W_pred[512 + tid]; }
  if (tid < 192) cgx_l[tid] = cgx[tid];
  if (tid >= 256 && tid < 384) uh_l[tid - 256] = uh[tid - 256];
  if (tid >= 384 && tid < 388) hm_l[tid - 384] = heads_map[tid - 384];
  float dw0 = dwv[0], dw1 = dwv[1];
  // prefetch offsets for the 5 (h,s) score pairs of this wave
  int poff[5];
#pragma unroll
  for (int q = 0; q < 5; ++q) { int p = wv * 5 + q; int hh = p / 10, s = p - hh * 10; poff[q] = s * 256 + hh * 64 + lane; }
  // ---- prologue prefetch (step 0) ----
  float pf_p4[5];
#pragma unroll
  for (int q = 0; q < 5; ++q) pf_p4[q] = P4s[(size_t)b * 2560 + poff[q]];
  float pf_sqv = 0.f;
  if (lane < 5) pf_sqv = SQVb[b * 40 + wv * 5 + lane];
  float pf_cg[10]; float pf_gxv = 0.f;
  if (tid >= 64 && tid < 256) {
    int c = tid - 64;
#pragma unroll
    for (int s = 0; s < 10; ++s) pf_cg[s] = Cg[(size_t)(b * 10 + s) * 192 + c];
    int rn = response[b];
    pf_gxv = GXV[(size_t)b * 384 + (rn ? 0 : 192) + c];
  } else {
#pragma unroll
    for (int s = 0; s < 10; ++s) pf_cg[s] = 0.f;
  }
  float pf_cbp = 0.f;
  if (wv == 5 && lane < 10) pf_cbp = cbp[b * 10 + lane];
  float pf_probc = 0.f;
  if (tid == 0) pf_probc = PROBC[b];
  float4 pf_pw = make_float4(0.f, 0.f, 0.f, 0.f), pf_pr = pf_pw;
  if (tid < 32) pf_pw = *(const float4*)&PW[((size_t)(b * 128 + 0)) * 128 + 4 * tid];
  else if (tid < 64) pf_pr = *(const float4*)&PR[((size_t)(b * 128 + 0)) * 128 + 4 * (tid - 32)];
  if (tid < 32) *(float4*)&PWl[4 * tid] = pf_pw;
  else if (tid < 64) *(float4*)&PRl[4 * (tid - 32)] = pf_pr;
  if (tid < 32) pf_pw = *(const float4*)&PW[((size_t)(b * 128 + 1)) * 128 + 4 * tid];
  else if (tid < 64) pf_pr = *(const float4*)&PR[((size_t)(b * 128 + 1)) * 128 + 4 * (tid - 32)];
  __syncthreads();

  for (int t = 0; t < 128; ++t) {
    int tn = (t < 127) ? t + 1 : 127;
    int tbn = tn * 64 + b;
    // ---- phase A: bg scores; gh partials; history weighted sums ----
    float hc = h_cur[lane];
    {
      float v[5];
#pragma unroll
      for (int q = 0; q < 5; ++q) v[q] = hc * pf_p4[q];
#pragma unroll
      for (int d = 32; d; d >>= 1) {
#pragma unroll
        for (int q = 0; q < 5; ++q) v[q] += __shfl_xor(v[q], d);
      }
#pragma unroll
      for (int q = 0; q < 5; ++q) if (lane == q) score_l[wv * 5 + q] = v[q] + pf_sqv;
    }
#pragma unroll
    for (int q = 0; q < 5; ++q) pf_p4[q] = P4s[(size_t)tbn * 2560 + poff[q]];
    if (lane < 5) pf_sqv = SQVb[tbn * 40 + wv * 5 + lane];
    {
      float l0 = 0.f, l1 = 0.f, l2 = 0.f;
#pragma unroll
      for (int ii = 0; ii < 8; ++ii) {
        float hv = h_cur[wv * 8 + ii];
        l0 += hv * wreg[ii][0]; l1 += hv * wreg[ii][1]; l2 += hv * wreg[ii][2];
      }
      redW[wv][cg3] = l0; redW[wv][cg3 + 1] = l1; redW[wv][cg3 + 2] = l2;
    }
    {
      float aR = 0.f, aA = 0.f;
      for (int j = wv; j <= t; j += 8) {
        float w = PWl[j], r = PRl[j], hv = h_hist[j][lane];
        aA += w * hv; aR += r * hv;
      }
      red8[wv][lane] = aR; red8[wv][64 + lane] = aA;
    }
    __syncthreads();
    // ---- phase B: hisA; gh final; per-head softmax max/sum ----
    if (tid < 64) {
      float sR = 0.f, sA = 0.f;
#pragma unroll
      for (int g = 0; g < 8; ++g) { sR += red8[g][tid]; sA += red8[g][64 + tid]; }
      hisA[tid] = sR; hisA[64 + tid] = sA - sR;
    } else if (tid < 256) {
      int c = tid - 64; float g = 0.f;
#pragma unroll
      for (int gg = 0; gg < 8; ++gg) g += redW[gg][c];
      gh_l[c] = g + b_hh[c];
    } else if (tid >= 448 && tid < 452) {
      int h = tid - 448;
      float mx = -1e30f;
#pragma unroll
      for (int s = 0; s < 10; ++s) mx = fmaxf(mx, score_l[h * 10 + s]);
      float sum = 0.f;
#pragma unroll
      for (int s = 0; s < 10; ++s) sum += __expf(score_l[h * 10 + s] - mx);
      sm_mx[h] = mx; sm_inv[h] = hm_l[h] / sum;
    }
    __syncthreads();
    // ---- phase C: his@Hmix partials; ws; phis; hwp ----
    {
      float l0 = 0.f, l1 = 0.f, l2 = 0.f;
#pragma unroll
      for (int ii = 0; ii < 16; ++ii) {
        float hv = hisA[wv * 16 + ii];
        l0 += hv * hreg[ii][0]; l1 += hv * hreg[ii][1]; l2 += hv * hreg[ii][2];
      }
      redW[wv][cg3] = l0; redW[wv][cg3 + 1] = l1; redW[wv][cg3 + 2] = l2;
    }
    if (tid >= 448 && tid < 458) {
      int s = tid - 448; float w = 0.f;
#pragma unroll
      for (int h = 0; h < 4; ++h) w += sm_inv[h] * __expf(score_l[h * 10 + s] - sm_mx[h]);
      ws_l[s] = w;
    }
    if (wv == 0) {
      float p = hisA[lane] * uh_l[lane] + hisA[64 + lane] * uh_l[64 + lane];
      p = wave_sum(p);
      if (lane == 0) phis_s = p;
    }
    if (wv == 6) {
      float p = hc * wph_l[lane];
      p = wave_sum(p);
      if (lane == 0) hwp_s = p;
    }
    __syncthreads();
    // ---- phase D: gx full; pbg ----
    if (tid >= 64 && tid < 256) {
      int c = tid - 64;
      float gbg = 0.f;
#pragma unroll
      for (int s = 0; s < 10; ++s) gbg += ws_l[s] * pf_cg[s];
      float gxh = 0.f;
#pragma unroll
      for (int g = 0; g < 8; ++g) gxh += redW[g][c];
      gx_l[c] = dw0 * gbg + dw1 * gxh + pf_gxv + cgx_l[c];
#pragma unroll
      for (int s = 0; s < 10; ++s) pf_cg[s] = Cg[(size_t)(tbn * 10 + s) * 192 + c];
      int rn = response[tbn];
      pf_gxv = GXV[(size_t)tbn * 384 + (rn ? 0 : 192) + c];
    }
    if (wv == 5) {
      float p = (lane < 10) ? ws_l[lane] * pf_cbp : 0.f;
      p = wave_sum(p);
      if (lane == 0) pbg_s = p;
      if (lane < 10) pf_cbp = cbp[tbn * 10 + lane];
    }
    __syncthreads();
    // ---- phase E: GRU; prob; PW/PR rotate ----
    if (tid < 64) {
      float xr = gx_l[tid], xz = gx_l[64 + tid], xn = gx_l[128 + tid];
      float hr = gh_l[tid], hz = gh_l[64 + tid], hn = gh_l[128 + tid];
      float r = 1.f / (1.f + __expf(-(xr + hr)));
      float z = 1.f / (1.f + __expf(-(xz + hz)));
      float n = tanhf(xn + r * hn);
      float hnew = (1.f - z) * n + z * h_cur[tid];
      h_cur[tid] = hnew;
      if (t < 127) h_hist[t + 1][tid] = hnew;
    }
    if (tid == 0) {
      out[b * 128 + t] = dw0 * pbg_s + dw1 * phis_s + hwp_s + pf_probc;
      pf_probc = PROBC[tbn];
    }
    if (tid < 32) *(float4*)&PWl[4 * tid] = pf_pw;
    else if (tid < 64) *(float4*)&PRl[4 * (tid - 32)] = pf_pr;
    {
      int rn2 = (t + 2 < 128) ? t + 2 : 127;
      if (tid < 32) pf_pw = *(const float4*)&PW[((size_t)(b * 128 + rn2)) * 128 + 4 * tid];
      else if (tid < 64) pf_pr = *(const float4*)&PR[((size_t)(b * 128 + rn2)) * 128 + 4 * (tid - 32)];
    }
    __syncthreads();
  }
}

// ---------------- launch ----------------
extern "C" void kernel_launch(void* const* d_in, const int* in_sizes, int n_in,
                              void* d_out, int out_size, void* d_ws, size_t ws_size,
                              hipStream_t stream) {
  const int* prob_id      = (const int*)d_in[0];
  const int* skills       = (const int*)d_in[1];
  const int* response     = (const int*)d_in[2];
  const int* bg_index     = (const int*)d_in[3];
  const int* mem_prob_ids = (const int*)d_in[4];
  const int* mem_resp     = (const int*)d_in[5];
  const int* mem_concepts = (const int*)d_in[6];
  const float* states_mem  = (const float*)d_in[7];
  const float* concept_emb = (const float*)d_in[8];
  const float* prob_emb    = (const float*)d_in[9];
  const float* W_pred   = (const float*)d_in[10];
  const float* b_pred   = (const float*)d_in[11];
  const float* W_ih     = (const float*)d_in[12];
  const float* W_hh     = (const float*)d_in[13];
  const float* b_ih     = (const float*)d_in[14];
  const float* b_hh     = (const float*)d_in[15];
  const float* W_batch  = (const float*)d_in[16];
  const float* b_batch  = (const float*)d_in[17];
  const float* W_bg     = (const float*)d_in[18];
  const float* b_bg     = (const float*)d_in[19];
  const float* W_bgint  = (const float*)d_in[20];
  const float* b_bgint  = (const float*)d_in[21];
  const float* W_hisint = (const float*)d_in[22];
  const float* b_hisint = (const float*)d_in[23];
  const float* W_inmap  = (const float*)d_in[24];
  const float* b_inmap  = (const float*)d_in[25];
  const float* dir_w    = (const float*)d_in[26];
  const float* heads_map= (const float*)d_in[27];
  float* out = (float*)d_out;

  float* w = (float*)d_ws;
  size_t off = 0;
  auto alloc = [&](size_t n) { float* p = w + off; off += n; return p; };
  float* M12    = alloc(640 * 192);
  float* B1     = alloc(192 * 640);
  float* Hmix   = alloc(128 * 192);
  float* WgT    = alloc(4 * 192 * 64);
  float* WBvcat = alloc(128 * 256);
  float* Bgxv   = alloc(128 * 384);
  float* c4     = alloc(256);
  float* cgx    = alloc(192);
  float* uh     = alloc(128);
  float* bgp    = alloc(384);
  float* c0     = alloc(1);
  float* dwv    = alloc(2);
  float* V      = alloc((size_t)8192 * 128);
  float* VT     = alloc((size_t)64 * 128 * 128);
  float* QV     = alloc((size_t)8192 * 256);
  float* RQ     = alloc((size_t)8192 * 768);
  float* GXV    = alloc((size_t)8192 * 384);
  float* S      = alloc((size_t)64 * 128 * 128);   // becomes PW in-place
  float* PR     = alloc((size_t)64 * 128 * 128);
  float* P4s    = alloc((size_t)NITEM * 256);
  float* Cg     = alloc((size_t)NITEM * 192);
  float* SQVb   = alloc((size_t)8192 * 40);
  float* cbp    = alloc((size_t)NITEM);
  float* PROBC  = alloc(8192);
  (void)ws_size; (void)in_sizes; (void)n_in; (void)out_size;

  build_v<<<8192, 64, 0, stream>>>(prob_id, skills, concept_emb, prob_emb, V, VT);
  gemm_f32<<<dim3(3, 10, 1), 256, 0, stream>>>(W_inmap, W_ih, M12, nullptr,
      640, 192, 256, 256, 192, 192, 0, 0, 0, 1.0f);
  k_small<<<1092, 256, 0, stream>>>(W_batch, W_bg, b_bg, W_bgint, b_bgint, W_hisint, b_hisint,
      W_ih, b_ih, b_inmap, W_pred, b_pred, dir_w, M12, B1, Hmix, WgT, WBvcat, Bgxv,
      c4, cgx, uh, bgp, c0, dwv);
  gemm_f32<<<dim3(4, 128, 1), 256, 0, stream>>>(V, WBvcat, QV, b_batch,
      8192, 256, 128, 128, 256, 256, 0, 0, 0, 1.0f);
  for (int h = 0; h < 4; ++h)
    gemm_f32<<<dim3(3, 128, 1), 256, 0, stream>>>(QV + h * 64, WgT + h * 12288, RQ + h * 192, nullptr,
        8192, 192, 64, 256, 192, 768, 0, 0, 0, 1.0f);
  gemm_f32<<<dim3(6, 128, 1), 256, 0, stream>>>(V, Bgxv, GXV, nullptr,
      8192, 384, 128, 128, 384, 384, 0, 0, 0, 1.0f);
  gemm_f32<<<dim3(2, 2, 64), 256, 0, stream>>>(V, VT, S, nullptr,
      128, 128, 128, 8192, 128, 128, 128, 16384, 16384, 0.08838834764831845f);
  prep_pw<<<8192, 64, 0, stream>>>(S, response, S, PR);
  big_gemm<<<dim3(640, 5, 1), 256, 0, stream>>>(bg_index, mem_prob_ids, mem_resp, mem_concepts,
      states_mem, concept_emb, prob_emb, B1, c4, P4s, Cg);
  k5<<<8192, 256, 0, stream>>>(bg_index, mem_prob_ids, mem_resp, mem_concepts,
      states_mem, concept_emb, prob_emb, RQ, QV, b_bg, bgp, V, W_pred, c0, SQVb, cbp, PROBC);
  seq_kernel<<<64, 512, 0, stream>>>(response, P4s, SQVb, Cg, GXV, cbp, PROBC,
      S, PR, Hmix, W_hh, b_hh, cgx, uh, W_pred, heads_map, dwv, out);
}

// Round 3
// 935.851 us; speedup vs baseline: 1.6996x; 1.3131x over previous
//
#include <hip/hip_runtime.h>
#include <hip/hip_bf16.h>

// ---------------- constants ----------------
#define TT 128
#define BB 64
#define DD 64
#define RR 20
#define SEE 10
#define HH 4
#define CC 4
#define NITEM (TT*BB*SEE)     // 81920
typedef __attribute__((ext_vector_type(8))) short short8;    // 8 bf16
typedef __attribute__((ext_vector_type(4))) float floatx4;   // MFMA acc

static __device__ __forceinline__ float wave_sum(float v) {
  v += __shfl_xor(v, 32); v += __shfl_xor(v, 16); v += __shfl_xor(v, 8);
  v += __shfl_xor(v, 4);  v += __shfl_xor(v, 2);  v += __shfl_xor(v, 1);
  return v;
}
static __device__ __forceinline__ float wave_max(float v) {
  v = fmaxf(v, __shfl_xor(v, 32)); v = fmaxf(v, __shfl_xor(v, 16)); v = fmaxf(v, __shfl_xor(v, 8));
  v = fmaxf(v, __shfl_xor(v, 4));  v = fmaxf(v, __shfl_xor(v, 2));  v = fmaxf(v, __shfl_xor(v, 1));
  return v;
}
static __device__ __forceinline__ unsigned short f2bf(float x) {
  __hip_bfloat16 h = __float2bfloat16(x);
  return *reinterpret_cast<unsigned short*>(&h);
}
static __device__ __forceinline__ unsigned int pack2(float lo, float hi) {
  return (unsigned int)f2bf(lo) | ((unsigned int)f2bf(hi) << 16);
}

// ---------------- build V (and V^T per b) ----------------
__global__ void build_v(const int* __restrict__ prob_id, const int* __restrict__ skills,
                        const float* __restrict__ concept_emb, const float* __restrict__ prob_emb,
                        float* __restrict__ V, float* __restrict__ VT) {
  int tb = blockIdx.x; int t = tb >> 6, b = tb & 63; int d = threadIdx.x;
  int pid = prob_id[tb];
  float pr = pid ? prob_emb[(pid - 1) * 64 + d] : 0.0f;
  int cnt = 0; float sum = 0.0f;
#pragma unroll
  for (int c = 0; c < 4; ++c) {
    int sk = skills[tb * 4 + c];
    if (sk) { ++cnt; sum += concept_emb[(sk - 1) * 64 + d]; }
  }
  float mean = sum / (float)(cnt ? cnt : 1);
  V[tb * 128 + d] = mean;
  V[tb * 128 + 64 + d] = pr;
  VT[b * 16384 + d * 128 + t] = mean;
  VT[b * 16384 + (64 + d) * 128 + t] = pr;
}

// ---------------- generic fp32 GEMM ----------------
__global__ __launch_bounds__(256) void gemm_f32(
    const float* __restrict__ A, const float* __restrict__ B, float* __restrict__ C,
    const float* __restrict__ bias, int M, int N, int K,
    int lda, int ldb, int ldc, long sA, long sB, long sC, float scale) {
  __shared__ __align__(16) float As[64 * 36];
  __shared__ __align__(16) float Bs[32 * 64];
  const float* Ab = A + (long)blockIdx.z * sA;
  const float* Bb = B + (long)blockIdx.z * sB;
  float* Cb = C + (long)blockIdx.z * sC;
  int m0 = blockIdx.y * 64, n0 = blockIdx.x * 64;
  int tid = threadIdx.x;
  int ti = tid & 15, tj = tid >> 4;
  float acc[4][4] = {};
  for (int kc = 0; kc < K; kc += 32) {
#pragma unroll
    for (int p = 0; p < 2; ++p) {
      int q = tid + 256 * p;
      int row = q >> 3, kq = q & 7;
      *(float4*)&As[row * 36 + 4 * kq] = *(const float4*)&Ab[(size_t)(m0 + row) * lda + kc + 4 * kq];
    }
#pragma unroll
    for (int p = 0; p < 2; ++p) {
      int q = tid + 256 * p;
      int k = q >> 4, nq = q & 15;
      *(float4*)&Bs[k * 64 + 4 * nq] = *(const float4*)&Bb[(size_t)(kc + k) * ldb + n0 + 4 * nq];
    }
    __syncthreads();
#pragma unroll
    for (int k4 = 0; k4 < 8; ++k4) {
      float4 av[4], bv[4];
#pragma unroll
      for (int m = 0; m < 4; ++m) av[m] = *(const float4*)&As[(ti + 16 * m) * 36 + 4 * k4];
#pragma unroll
      for (int kk = 0; kk < 4; ++kk) bv[kk] = *(const float4*)&Bs[(4 * k4 + kk) * 64 + 4 * tj];
#pragma unroll
      for (int m = 0; m < 4; ++m) {
        const float* ap = (const float*)&av[m];
#pragma unroll
        for (int kk = 0; kk < 4; ++kk) {
          float a = ap[kk];
          acc[m][0] += a * bv[kk].x; acc[m][1] += a * bv[kk].y;
          acc[m][2] += a * bv[kk].z; acc[m][3] += a * bv[kk].w;
        }
      }
    }
    __syncthreads();
  }
  float4 bq = make_float4(0.f, 0.f, 0.f, 0.f);
  if (bias) bq = *(const float4*)&bias[n0 + 4 * tj];
#pragma unroll
  for (int m = 0; m < 4; ++m) {
    int row = m0 + ti + 16 * m;
    float4 o;
    o.x = acc[m][0] * scale + bq.x; o.y = acc[m][1] * scale + bq.y;
    o.z = acc[m][2] * scale + bq.z; o.w = acc[m][3] * scale + bq.w;
    *(float4*)&Cb[(size_t)row * ldc + n0 + 4 * tj] = o;
  }
}

// ---------------- small weight folds (needs M12) ----------------
// B1T (bf16, [n 640][k 192]) replaces fp32 B1: written transposed for MFMA.
__global__ __launch_bounds__(256) void k_small(
    const float* __restrict__ W_batch, const float* __restrict__ W_bg, const float* __restrict__ b_bg,
    const float* __restrict__ W_bgint, const float* __restrict__ b_bgint,
    const float* __restrict__ W_hisint, const float* __restrict__ b_hisint,
    const float* __restrict__ W_ih, const float* __restrict__ b_ih, const float* __restrict__ b_inmap,
    const float* __restrict__ W_pred, const float* __restrict__ b_pred, const float* __restrict__ dir_w,
    const float* __restrict__ M12, unsigned short* __restrict__ B1T, float* __restrict__ Hmix,
    float* __restrict__ WgT, float* __restrict__ WBvcat, float* __restrict__ Bgxv,
    float* __restrict__ c4, float* __restrict__ cgx, float* __restrict__ uh,
    float* __restrict__ bgp, float* __restrict__ c0, float* __restrict__ dwv) {
  int idx = blockIdx.x * 256 + threadIdx.x;
  const int R0 = 49152, R1 = 86016, R2 = 122880, R3 = 147456, R4 = 196608,
            R5 = 229376, R6 = 278528, R7 = 278784, R8 = 278976, R9 = 279104,
            R10 = 279488, R11 = 279489, R12 = 279491;
  if (idx < R0) {
    int k = idx >> 8, n = idx & 255; int h = n >> 6, i = n & 63;
    float s = 0.f;
    for (int d = 0; d < 64; ++d) s += W_bg[h * 12288 + k * 64 + d] * W_batch[h * 12288 + i * 64 + d];
    B1T[n * 192 + k] = f2bf(s);
  } else if (idx < R1) {
    int r = idx - R0; int k = r / 192, c = r - k * 192;
    float s = 0.f;
    for (int j = 0; j < 384; ++j) s += W_bgint[k * 384 + j] * M12[j * 192 + c];
    B1T[(256 + c) * 192 + k] = f2bf(s);
  } else if (idx < R2) {
    int r = idx - R1; int k = r / 192, c = r - k * 192;
    float s = 0.f;
    for (int j = 0; j < 384; ++j) s += W_bgint[(192 + k) * 384 + j] * M12[j * 192 + c];
    B1T[(448 + c) * 192 + k] = f2bf(s);
  } else if (idx < R3) {
    int r = idx - R2; int i = r / 192, c = r - i * 192;
    float s = 0.f;
    for (int j = 0; j < 384; ++j) s += W_hisint[i * 384 + j] * M12[j * 192 + c];
    Hmix[i * 192 + c] = s;
  } else if (idx < R4) {
    int r = idx - R3; int h = r / 12288; int rem = r - h * 12288; int d = rem / 192, k = rem - d * 192;
    WgT[r] = W_bg[h * 12288 + k * 64 + d];
  } else if (idx < R5) {
    int r = idx - R4; int i = r >> 8, n = r & 255; int h = n >> 6, d = n & 63;
    WBvcat[r] = W_batch[h * 12288 + (64 + i) * 64 + d];
  } else if (idx < R6) {
    int r = idx - R5; int i = r / 384, c = r - i * 384;
    Bgxv[r] = (c < 192) ? M12[(384 + i) * 192 + c] : M12[(512 + i) * 192 + (c - 192)];
  } else if (idx < R7) {
    int n = idx - R6; int h = n >> 6, i = n & 63;
    float s = 0.f;
    for (int d = 0; d < 64; ++d) s += W_batch[h * 12288 + i * 64 + d] * b_bg[h * 64 + d];
    c4[n] = s;
  } else if (idx < R8) {
    int c = idx - R7;
    float e0 = __expf(dir_w[0]), e1 = __expf(dir_w[1]);
    float dw0 = e0 / (e0 + e1), dw1 = e1 / (e0 + e1);
    float s = b_ih[c];
    for (int i = 0; i < 256; ++i) s += b_inmap[i] * W_ih[i * 192 + c];
    for (int k = 0; k < 384; ++k) s += (dw0 * b_bgint[k] + dw1 * b_hisint[k]) * M12[k * 192 + c];
    cgx[c] = s;
  } else if (idx < R9) {
    int i = idx - R8;
    float s = 0.f;
    for (int j = 0; j < 384; ++j) s += W_hisint[i * 384 + j] * W_pred[j];
    uh[i] = s;
  } else if (idx < R10) {
    int k = idx - R9;
    float s = 0.f;
    for (int j = 0; j < 384; ++j) s += W_bgint[k * 384 + j] * W_pred[j];
    bgp[k] = s;
  } else if (idx < R11) {
    float e0 = __expf(dir_w[0]), e1 = __expf(dir_w[1]);
    float dw0 = e0 / (e0 + e1), dw1 = e1 / (e0 + e1);
    float s = b_pred[0];
    for (int k = 0; k < 384; ++k) s += (dw0 * b_bgint[k] + dw1 * b_hisint[k]) * W_pred[k];
    c0[0] = s;
  } else if (idx < R12) {
    float e0 = __expf(dir_w[0]), e1 = __expf(dir_w[1]);
    dwv[idx - R11] = (idx == R11) ? e0 / (e0 + e1) : e1 / (e0 + e1);
  }
}

// ---------------- big gather-GEMM via bf16 MFMA: P4s/Cg ----------------
// 640 blocks; each gathers a 128x192 A-tile (bf16, LDS) ONCE, then loops over
// all 5 col-tiles of B1T (streamed in 32-K chunks). 4 waves x 64x64 subtile.
#define APAD 200   // bf16 stride: 2-way max bank aliasing (free)
#define BPAD 40
__global__ __launch_bounds__(256) void big_gemm(
    const int* __restrict__ bg_index, const int* __restrict__ mem_prob_ids,
    const int* __restrict__ mem_resp, const int* __restrict__ mem_concepts,
    const float* __restrict__ states_mem, const float* __restrict__ concept_emb,
    const float* __restrict__ prob_emb, const unsigned short* __restrict__ B1T,
    const float* __restrict__ c4, float* __restrict__ P4s, float* __restrict__ Cg) {
  __shared__ unsigned short As[128 * APAD];   // 51200 B
  __shared__ unsigned short Bs[128 * BPAD];   // 10240 B
  __shared__ int bgi_l[128]; __shared__ int rf_l[128];
  int mt = blockIdx.x;
  int tid = threadIdx.x;
  int lane = tid & 63, wv = tid >> 6;
  if (tid < 128) {
    int item = mt * 128 + tid;
    int t = item / 640; int rem = item - t * 640; int b = rem / 10; int s = rem - b * 10;
    int g = bg_index[(t * 64 + b) * 20 + s];
    bgi_l[tid] = g;
    rf_l[tid] = mem_resp[g];
  }
  __syncthreads();
  // ---- gather A-tile as bf16 into LDS (each wave: rows [wv*32, wv*32+32)) ----
  {
    int half = lane >> 5;       // two rows per iteration (one per half-wave)
    int hl = lane & 31;         // element-pair index: d = 2*hl
    for (int rr = 0; rr < 32; rr += 2) {
      int r = wv * 32 + rr + half;
      int g = bgi_l[r];
      float2 sv = *(const float2*)&states_mem[g * 64 + 2 * hl];
      *(unsigned int*)&As[r * APAD + 2 * hl] = pack2(sv.x, sv.y);
      float s0 = 0.f, s1 = 0.f; int cnt = 0;
#pragma unroll
      for (int c = 0; c < 4; ++c) {
        int sk = mem_concepts[g * 4 + c];
        if (sk) { ++cnt; float2 e = *(const float2*)&concept_emb[(sk - 1) * 64 + 2 * hl]; s0 += e.x; s1 += e.y; }
      }
      float inv = 1.0f / (float)(cnt ? cnt : 1);
      *(unsigned int*)&As[r * APAD + 64 + 2 * hl] = pack2(s0 * inv, s1 * inv);
      int pid = mem_prob_ids[g];
      float2 pv = make_float2(0.f, 0.f);
      if (pid) pv = *(const float2*)&prob_emb[(pid - 1) * 64 + 2 * hl];
      *(unsigned int*)&As[r * APAD + 128 + 2 * hl] = pack2(pv.x, pv.y);
    }
  }
  int l15 = lane & 15, q = lane >> 4;
  int mh = (wv & 1) * 64, nh = (wv >> 1) * 64;
  const float invs192 = 0.07216878364870323f; // 1/sqrt(192)
  for (int nt = 0; nt < 5; ++nt) {
    int n0 = nt * 128;
    floatx4 acc[4][4];
#pragma unroll
    for (int mi = 0; mi < 4; ++mi)
#pragma unroll
      for (int ni = 0; ni < 4; ++ni)
#pragma unroll
        for (int r = 0; r < 4; ++r) acc[mi][ni][r] = 0.f;
    for (int kc = 0; kc < 6; ++kc) {
      __syncthreads();   // Bs consumed by previous iter / As gather done
#pragma unroll
      for (int u = 0; u < 2; ++u) {
        int un = tid * 2 + u;            // 0..511 : 128 n-rows x 4 k-octets
        int n = un >> 2, kk = (un & 3) * 8;
        *(float4*)&Bs[n * BPAD + kk] = *(const float4*)&B1T[(size_t)(n0 + n) * 192 + kc * 32 + kk];
      }
      __syncthreads();
      short8 a[4], bfr[4];
#pragma unroll
      for (int mi = 0; mi < 4; ++mi)
        a[mi] = *reinterpret_cast<const short8*>(&As[(mh + mi * 16 + l15) * APAD + kc * 32 + q * 8]);
#pragma unroll
      for (int ni = 0; ni < 4; ++ni)
        bfr[ni] = *reinterpret_cast<const short8*>(&Bs[(nh + ni * 16 + l15) * BPAD + q * 8]);
#pragma unroll
      for (int mi = 0; mi < 4; ++mi)
#pragma unroll
        for (int ni = 0; ni < 4; ++ni)
          acc[mi][ni] = __builtin_amdgcn_mfma_f32_16x16x32_bf16(a[mi], bfr[ni], acc[mi][ni], 0, 0, 0);
    }
    // ---- epilogue for this col-tile ----
    float c4v[4];
    if (n0 + nh < 256) {
#pragma unroll
      for (int ni = 0; ni < 4; ++ni) c4v[ni] = c4[n0 + nh + ni * 16 + l15];
    }
#pragma unroll
    for (int mi = 0; mi < 4; ++mi) {
#pragma unroll
      for (int r = 0; r < 4; ++r) {
        int row = mh + mi * 16 + q * 4 + r;
        int item = mt * 128 + row;
        int rf = rf_l[row];
#pragma unroll
        for (int ni = 0; ni < 4; ++ni) {
          int coln = n0 + nh + ni * 16 + l15;
          float o = acc[mi][ni][r];
          if (coln < 256) {
            P4s[(size_t)item * 256 + coln] = (o + c4v[ni]) * invs192;
          } else if (coln < 448) {
            if (rf) Cg[(size_t)item * 192 + (coln - 256)] = o;
          } else {
            if (!rf) Cg[(size_t)item * 192 + (coln - 448)] = o;
          }
        }
      }
    }
  }
}

// ---------------- per-(t,b) smalls: SQV, cbp, PROBC ----------------
__global__ __launch_bounds__(256) void k5(
    const int* __restrict__ bg_index, const int* __restrict__ mem_prob_ids,
    const int* __restrict__ mem_resp, const int* __restrict__ mem_concepts,
    const float* __restrict__ states_mem, const float* __restrict__ concept_emb,
    const float* __restrict__ prob_emb, const float* __restrict__ RQ, const float* __restrict__ QV,
    const float* __restrict__ b_bg, const float* __restrict__ bgp, const float* __restrict__ V,
    const float* __restrict__ W_pred, const float* __restrict__ c0,
    float* __restrict__ SQVb, float* __restrict__ cbp, float* __restrict__ PROBC) {
  int tb = blockIdx.x;
  int tid = threadIdx.x;
  int lane = tid & 63, wv = tid >> 6;
  __shared__ float ahv[10 * 196];
  __shared__ float rql[4 * 196];
  __shared__ float bgpl[384];
  __shared__ int bgi_l[10]; __shared__ int rf_s[10];
  __shared__ float cqb[4];
  if (tid < 10) { int g = bg_index[tb * 20 + tid]; bgi_l[tid] = g; rf_s[tid] = mem_resp[g]; }
  for (int i = tid; i < 384; i += 256) bgpl[i] = bgp[i];
  for (int i = tid; i < 768; i += 256) { int h = i / 192, c = i - h * 192; rql[h * 196 + c] = RQ[(size_t)tb * 768 + i]; }
  if (tid < 4) {
    float s = 0.f;
    for (int d = 0; d < 64; ++d) s += QV[tb * 256 + tid * 64 + d] * b_bg[tid * 64 + d];
    cqb[tid] = s;
  }
  __syncthreads();
  for (int s = 0; s < 10; ++s) {
    if (tid < 192) {
      int g = bgi_l[s]; float v;
      if (tid < 64) v = states_mem[g * 64 + tid];
      else if (tid < 128) {
        int d = tid - 64; float sum = 0.f; int cnt = 0;
#pragma unroll
        for (int c = 0; c < 4; ++c) { int sk = mem_concepts[g * 4 + c]; if (sk) { ++cnt; sum += concept_emb[(sk - 1) * 64 + d]; } }
        v = sum / (float)(cnt ? cnt : 1);
      } else {
        int pid = mem_prob_ids[g];
        v = pid ? prob_emb[(pid - 1) * 64 + (tid - 128)] : 0.0f;
      }
      ahv[s * 196 + tid] = v;
    }
  }
  __syncthreads();
  const float invs192 = 0.07216878364870323f;
  for (int q = 0; q < 10; ++q) {
    float v = ahv[q * 196 + lane] * rql[wv * 196 + lane]
            + ahv[q * 196 + 64 + lane] * rql[wv * 196 + 64 + lane]
            + ahv[q * 196 + 128 + lane] * rql[wv * 196 + 128 + lane];
    v = wave_sum(v);
    if (lane == 0) SQVb[tb * 40 + wv * 10 + q] = (v + cqb[wv]) * invs192;
  }
  if (wv == 0) {
    for (int q = 0; q < 10; ++q) {
      int off = rf_s[q] ? 0 : 192;
      float v = ahv[q * 196 + lane] * bgpl[off + lane]
              + ahv[q * 196 + 64 + lane] * bgpl[off + 64 + lane]
              + ahv[q * 196 + 128 + lane] * bgpl[off + 128 + lane];
      v = wave_sum(v);
      if (lane == 0) cbp[tb * 10 + q] = v;
    }
  }
  if (wv == 1) {
    float v = V[tb * 128 + lane] * W_pred[384 + lane] + V[tb * 128 + 64 + lane] * W_pred[448 + lane];
    v = wave_sum(v);
    if (lane == 0) PROBC[tb] = v + c0[0];
  }
}

// ---------------- precompute history softmax weights ----------------
__global__ __launch_bounds__(64) void prep_pw(const float* S, const int* response,
                                              float* PW, float* PR) {
  int bt = blockIdx.x; int b = bt >> 7, t = bt & 127;
  int lane = threadIdx.x;
  size_t row = (size_t)bt * 128;
  float s0 = (lane == 0) ? 0.f : ((lane <= t) ? S[row + lane - 1] : -1e30f);
  float s1 = (lane + 64 <= t) ? S[row + lane + 63] : -1e30f;
  float m = wave_max(fmaxf(s0, s1));
  float e0 = (lane <= t) ? __expf(s0 - m) : 0.f;
  float e1 = (lane + 64 <= t) ? __expf(s1 - m) : 0.f;
  float inv = 1.f / wave_sum(e0 + e1);
  float r0 = (lane >= 1) ? (float)response[(lane - 1) * 64 + b] : 0.f;
  float r1 = (float)response[(lane + 63) * 64 + b];
  PW[row + lane] = e0 * inv;
  PW[row + 64 + lane] = e1 * inv;
  PR[row + lane] = e0 * inv * r0;
  PR[row + 64 + lane] = e1 * inv * r1;
}

// ---------------- sequential recurrence: one block per b ----------------
__global__ __launch_bounds__(512) void seq_kernel(
    const int* __restrict__ response, const float* __restrict__ P4s,
    const float* __restrict__ SQVb, const float* __restrict__ Cg,
    const float* __restrict__ GXV, const float* __restrict__ cbp,
    const float* __restrict__ PROBC, const float* __restrict__ PW,
    const float* __restrict__ PR, const float* __restrict__ Hmix,
    const float* __restrict__ W_hh, const float* __restrict__ b_hh,
    const float* __restrict__ cgx, const float* __restrict__ uh,
    const float* __restrict__ W_pred, const float* __restrict__ heads_map,
    const float* __restrict__ dwv, float* __restrict__ out) {
  int b = blockIdx.x;
  int tid = threadIdx.x;
  int lane = tid & 63, wv = tid >> 6;
  int cg3 = lane * 3;
  float hreg[16][3], wreg[8][3];
#pragma unroll
  for (int ii = 0; ii < 16; ++ii)
#pragma unroll
    for (int cc = 0; cc < 3; ++cc) hreg[ii][cc] = Hmix[(wv * 16 + ii) * 192 + cg3 + cc];
#pragma unroll
  for (int ii = 0; ii < 8; ++ii)
#pragma unroll
    for (int cc = 0; cc < 3; ++cc) wreg[ii][cc] = W_hh[(wv * 8 + ii) * 192 + cg3 + cc];
  __shared__ float h_hist[128][64];
  __shared__ __align__(16) float PWl[128];
  __shared__ __align__(16) float PRl[128];
  __shared__ float h_cur[64];
  __shared__ float score_l[40], ws_l[10];
  __shared__ float hisA[128];
  __shared__ float red8[8][128];
  __shared__ float redW[8][192];
  __shared__ float gx_l[192], gh_l[192];
  __shared__ float cgx_l[192], uh_l[128], wph_l[64], hm_l[4];
  __shared__ float sm_mx[4], sm_inv[4];
  __shared__ float phis_s, hwp_s, pbg_s;
  if (tid < 64) { h_cur[tid] = 0.f; h_hist[0][tid] = 0.f; wph_l[tid] = W_pred[512 + tid]; }
  if (tid < 192) cgx_l[tid] = cgx[tid];
  if (tid >= 256 && tid < 384) uh_l[tid - 256] = uh[tid - 256];
  if (tid >= 384 && tid < 388) hm_l[tid - 384] = heads_map[tid - 384];
  float dw0 = dwv[0], dw1 = dwv[1];
  int poff[5];
#pragma unroll
  for (int q = 0; q < 5; ++q) { int p = wv * 5 + q; int hh = p / 10, s = p - hh * 10; poff[q] = s * 256 + hh * 64 + lane; }
  float pf_p4[5];
#pragma unroll
  for (int q = 0; q < 5; ++q) pf_p4[q] = P4s[(size_t)b * 2560 + poff[q]];
  float pf_sqv = 0.f;
  if (lane < 5) pf_sqv = SQVb[b * 40 + wv * 5 + lane];
  float pf_cg[10]; float pf_gxv = 0.f;
  if (tid >= 64 && tid < 256) {
    int c = tid - 64;
#pragma unroll
    for (int s = 0; s < 10; ++s) pf_cg[s] = Cg[(size_t)(b * 10 + s) * 192 + c];
    int rn = response[b];
    pf_gxv = GXV[(size_t)b * 384 + (rn ? 0 : 192) + c];
  } else {
#pragma unroll
    for (int s = 0; s < 10; ++s) pf_cg[s] = 0.f;
  }
  float pf_cbp = 0.f;
  if (wv == 5 && lane < 10) pf_cbp = cbp[b * 10 + lane];
  float pf_probc = 0.f;
  if (tid == 0) pf_probc = PROBC[b];
  float4 pf_pw = make_float4(0.f, 0.f, 0.f, 0.f), pf_pr = pf_pw;
  if (tid < 32) pf_pw = *(const float4*)&PW[((size_t)(b * 128 + 0)) * 128 + 4 * tid];
  else if (tid < 64) pf_pr = *(const float4*)&PR[((size_t)(b * 128 + 0)) * 128 + 4 * (tid - 32)];
  if (tid < 32) *(float4*)&PWl[4 * tid] = pf_pw;
  else if (tid < 64) *(float4*)&PRl[4 * (tid - 32)] = pf_pr;
  if (tid < 32) pf_pw = *(const float4*)&PW[((size_t)(b * 128 + 1)) * 128 + 4 * tid];
  else if (tid < 64) pf_pr = *(const float4*)&PR[((size_t)(b * 128 + 1)) * 128 + 4 * (tid - 32)];
  __syncthreads();

  for (int t = 0; t < 128; ++t) {
    int tn = (t < 127) ? t + 1 : 127;
    int tbn = tn * 64 + b;
    float hc = h_cur[lane];
    {
      float v[5];
#pragma unroll
      for (int q = 0; q < 5; ++q) v[q] = hc * pf_p4[q];
#pragma unroll
      for (int d = 32; d; d >>= 1) {
#pragma unroll
        for (int q = 0; q < 5; ++q) v[q] += __shfl_xor(v[q], d);
      }
#pragma unroll
      for (int q = 0; q < 5; ++q) if (lane == q) score_l[wv * 5 + q] = v[q] + pf_sqv;
    }
#pragma unroll
    for (int q = 0; q < 5; ++q) pf_p4[q] = P4s[(size_t)tbn * 2560 + poff[q]];
    if (lane < 5) pf_sqv = SQVb[tbn * 40 + wv * 5 + lane];
    {
      float l0 = 0.f, l1 = 0.f, l2 = 0.f;
#pragma unroll
      for (int ii = 0; ii < 8; ++ii) {
        float hv = h_cur[wv * 8 + ii];
        l0 += hv * wreg[ii][0]; l1 += hv * wreg[ii][1]; l2 += hv * wreg[ii][2];
      }
      redW[wv][cg3] = l0; redW[wv][cg3 + 1] = l1; redW[wv][cg3 + 2] = l2;
    }
    {
      float aR = 0.f, aA = 0.f;
      for (int j = wv; j <= t; j += 8) {
        float w = PWl[j], r = PRl[j], hv = h_hist[j][lane];
        aA += w * hv; aR += r * hv;
      }
      red8[wv][lane] = aR; red8[wv][64 + lane] = aA;
    }
    __syncthreads();
    if (tid < 64) {
      float sR = 0.f, sA = 0.f;
#pragma unroll
      for (int g = 0; g < 8; ++g) { sR += red8[g][tid]; sA += red8[g][64 + tid]; }
      hisA[tid] = sR; hisA[64 + tid] = sA - sR;
    } else if (tid < 256) {
      int c = tid - 64; float g = 0.f;
#pragma unroll
      for (int gg = 0; gg < 8; ++gg) g += redW[gg][c];
      gh_l[c] = g + b_hh[c];
    } else if (tid >= 448 && tid < 452) {
      int h = tid - 448;
      float mx = -1e30f;
#pragma unroll
      for (int s = 0; s < 10; ++s) mx = fmaxf(mx, score_l[h * 10 + s]);
      float sum = 0.f;
#pragma unroll
      for (int s = 0; s < 10; ++s) sum += __expf(score_l[h * 10 + s] - mx);
      sm_mx[h] = mx; sm_inv[h] = hm_l[h] / sum;
    }
    __syncthreads();
    {
      float l0 = 0.f, l1 = 0.f, l2 = 0.f;
#pragma unroll
      for (int ii = 0; ii < 16; ++ii) {
        float hv = hisA[wv * 16 + ii];
        l0 += hv * hreg[ii][0]; l1 += hv * hreg[ii][1]; l2 += hv * hreg[ii][2];
      }
      redW[wv][cg3] = l0; redW[wv][cg3 + 1] = l1; redW[wv][cg3 + 2] = l2;
    }
    if (tid >= 448 && tid < 458) {
      int s = tid - 448; float w = 0.f;
#pragma unroll
      for (int h = 0; h < 4; ++h) w += sm_inv[h] * __expf(score_l[h * 10 + s] - sm_mx[h]);
      ws_l[s] = w;
    }
    if (wv == 0) {
      float p = hisA[lane] * uh_l[lane] + hisA[64 + lane] * uh_l[64 + lane];
      p = wave_sum(p);
      if (lane == 0) phis_s = p;
    }
    if (wv == 6) {
      float p = hc * wph_l[lane];
      p = wave_sum(p);
      if (lane == 0) hwp_s = p;
    }
    __syncthreads();
    if (tid >= 64 && tid < 256) {
      int c = tid - 64;
      float gbg = 0.f;
#pragma unroll
      for (int s = 0; s < 10; ++s) gbg += ws_l[s] * pf_cg[s];
      float gxh = 0.f;
#pragma unroll
      for (int g = 0; g < 8; ++g) gxh += redW[g][c];
      gx_l[c] = dw0 * gbg + dw1 * gxh + pf_gxv + cgx_l[c];
#pragma unroll
      for (int s = 0; s < 10; ++s) pf_cg[s] = Cg[(size_t)(tbn * 10 + s) * 192 + c];
      int rn = response[tbn];
      pf_gxv = GXV[(size_t)tbn * 384 + (rn ? 0 : 192) + c];
    }
    if (wv == 5) {
      float p = (lane < 10) ? ws_l[lane] * pf_cbp : 0.f;
      p = wave_sum(p);
      if (lane == 0) pbg_s = p;
      if (lane < 10) pf_cbp = cbp[tbn * 10 + lane];
    }
    __syncthreads();
    if (tid < 64) {
      float xr = gx_l[tid], xz = gx_l[64 + tid], xn = gx_l[128 + tid];
      float hr = gh_l[tid], hz = gh_l[64 + tid], hn = gh_l[128 + tid];
      float r = 1.f / (1.f + __expf(-(xr + hr)));
      float z = 1.f / (1.f + __expf(-(xz + hz)));
      float n = tanhf(xn + r * hn);
      float hnew = (1.f - z) * n + z * h_cur[tid];
      h_cur[tid] = hnew;
      if (t < 127) h_hist[t + 1][tid] = hnew;
    }
    if (tid == 0) {
      out[b * 128 + t] = dw0 * pbg_s + dw1 * phis_s + hwp_s + pf_probc;
      pf_probc = PROBC[tbn];
    }
    if (tid < 32) *(float4*)&PWl[4 * tid] = pf_pw;
    else if (tid < 64) *(float4*)&PRl[4 * (tid - 32)] = pf_pr;
    {
      int rn2 = (t + 2 < 128) ? t + 2 : 127;
      if (tid < 32) pf_pw = *(const float4*)&PW[((size_t)(b * 128 + rn2)) * 128 + 4 * tid];
      else if (tid < 64) pf_pr = *(const float4*)&PR[((size_t)(b * 128 + rn2)) * 128 + 4 * (tid - 32)];
    }
    __syncthreads();
  }
}

// ---------------- launch ----------------
extern "C" void kernel_launch(void* const* d_in, const int* in_sizes, int n_in,
                              void* d_out, int out_size, void* d_ws, size_t ws_size,
                              hipStream_t stream) {
  const int* prob_id      = (const int*)d_in[0];
  const int* skills       = (const int*)d_in[1];
  const int* response     = (const int*)d_in[2];
  const int* bg_index     = (const int*)d_in[3];
  const int* mem_prob_ids = (const int*)d_in[4];
  const int* mem_resp     = (const int*)d_in[5];
  const int* mem_concepts = (const int*)d_in[6];
  const float* states_mem  = (const float*)d_in[7];
  const float* concept_emb = (const float*)d_in[8];
  const float* prob_emb    = (const float*)d_in[9];
  const float* W_pred   = (const float*)d_in[10];
  const float* b_pred   = (const float*)d_in[11];
  const float* W_ih     = (const float*)d_in[12];
  const float* W_hh     = (const float*)d_in[13];
  const float* b_ih     = (const float*)d_in[14];
  const float* b_hh     = (const float*)d_in[15];
  const float* W_batch  = (const float*)d_in[16];
  const float* b_batch  = (const float*)d_in[17];
  const float* W_bg     = (const float*)d_in[18];
  const float* b_bg     = (const float*)d_in[19];
  const float* W_bgint  = (const float*)d_in[20];
  const float* b_bgint  = (const float*)d_in[21];
  const float* W_hisint = (const float*)d_in[22];
  const float* b_hisint = (const float*)d_in[23];
  const float* W_inmap  = (const float*)d_in[24];
  const float* b_inmap  = (const float*)d_in[25];
  const float* dir_w    = (const float*)d_in[26];
  const float* heads_map= (const float*)d_in[27];
  float* out = (float*)d_out;

  float* w = (float*)d_ws;
  size_t off = 0;
  auto alloc = [&](size_t n) { float* p = w + off; off += (n + 3) & ~(size_t)3; return p; };
  float* M12    = alloc(640 * 192);
  unsigned short* B1T = (unsigned short*)alloc(640 * 192 / 2);  // bf16 [640 n][192 k]
  float* Hmix   = alloc(128 * 192);
  float* WgT    = alloc(4 * 192 * 64);
  float* WBvcat = alloc(128 * 256);
  float* Bgxv   = alloc(128 * 384);
  float* c4     = alloc(256);
  float* cgx    = alloc(192);
  float* uh     = alloc(128);
  float* bgp    = alloc(384);
  float* c0     = alloc(1);
  float* dwv    = alloc(2);
  float* V      = alloc((size_t)8192 * 128);
  float* VT     = alloc((size_t)64 * 128 * 128);
  float* QV     = alloc((size_t)8192 * 256);
  float* RQ     = alloc((size_t)8192 * 768);
  float* GXV    = alloc((size_t)8192 * 384);
  float* S      = alloc((size_t)64 * 128 * 128);   // becomes PW in-place
  float* PR     = alloc((size_t)64 * 128 * 128);
  float* P4s    = alloc((size_t)NITEM * 256);
  float* Cg     = alloc((size_t)NITEM * 192);
  float* SQVb   = alloc((size_t)8192 * 40);
  float* cbp    = alloc((size_t)NITEM);
  float* PROBC  = alloc(8192);
  (void)ws_size; (void)in_sizes; (void)n_in; (void)out_size;

  build_v<<<8192, 64, 0, stream>>>(prob_id, skills, concept_emb, prob_emb, V, VT);
  gemm_f32<<<dim3(3, 10, 1), 256, 0, stream>>>(W_inmap, W_ih, M12, nullptr,
      640, 192, 256, 256, 192, 192, 0, 0, 0, 1.0f);
  k_small<<<1092, 256, 0, stream>>>(W_batch, W_bg, b_bg, W_bgint, b_bgint, W_hisint, b_hisint,
      W_ih, b_ih, b_inmap, W_pred, b_pred, dir_w, M12, B1T, Hmix, WgT, WBvcat, Bgxv,
      c4, cgx, uh, bgp, c0, dwv);
  gemm_f32<<<dim3(4, 128, 1), 256, 0, stream>>>(V, WBvcat, QV, b_batch,
      8192, 256, 128, 128, 256, 256, 0, 0, 0, 1.0f);
  for (int h = 0; h < 4; ++h)
    gemm_f32<<<dim3(3, 128, 1), 256, 0, stream>>>(QV + h * 64, WgT + h * 12288, RQ + h * 192, nullptr,
        8192, 192, 64, 256, 192, 768, 0, 0, 0, 1.0f);
  gemm_f32<<<dim3(6, 128, 1), 256, 0, stream>>>(V, Bgxv, GXV, nullptr,
      8192, 384, 128, 128, 384, 384, 0, 0, 0, 1.0f);
  gemm_f32<<<dim3(2, 2, 64), 256, 0, stream>>>(V, VT, S, nullptr,
      128, 128, 128, 8192, 128, 128, 128, 16384, 16384, 0.08838834764831845f);
  prep_pw<<<8192, 64, 0, stream>>>(S, response, S, PR);
  big_gemm<<<dim3(640), 256, 0, stream>>>(bg_index, mem_prob_ids, mem_resp, mem_concepts,
      states_mem, concept_emb, prob_emb, B1T, c4, P4s, Cg);
  k5<<<8192, 256, 0, stream>>>(bg_index, mem_prob_ids, mem_resp, mem_concepts,
      states_mem, concept_emb, prob_emb, RQ, QV, b_bg, bgp, V, W_pred, c0, SQVb, cbp, PROBC);
  seq_kernel<<<64, 512, 0, stream>>>(response, P4s, SQVb, Cg, GXV, cbp, PROBC,
      S, PR, Hmix, W_hh, b_hh, cgx, uh, W_pred, heads_map, dwv, out);
}